// Round 1
// baseline (781.048 us; speedup 1.0000x reference)
//
#include <hip/hip_runtime.h>

#define HH 64
#define WWD 64
#define CIN 256
#define OUTC 256
#define BB 4
#define KK 9
#define PX 32   // pixels per block in main kernel

// ---------------------------------------------------------------------------
// Kernel 1: offset conv (27 out channels), channel-split into 4 partials.
// grid: (16 tiles of 16x16, B, 4 channel-quarters), block 256 (one px/thread)
// ---------------------------------------------------------------------------
__global__ __launch_bounds__(256) void k_off_partial(const float* __restrict__ x,
                                                     const float* __restrict__ w_off,
                                                     float* __restrict__ om_part) {
    const int tile = blockIdx.x;
    const int b    = blockIdx.y;
    const int cc   = blockIdx.z;
    const int ty0 = (tile >> 2) << 4;
    const int tx0 = (tile & 3) << 4;
    const int tid = threadIdx.x;
    const int tyl = tid >> 4;
    const int txl = tid & 15;

    __shared__ float xs[4][18 * 18];

    float acc[27];
#pragma unroll
    for (int i = 0; i < 27; ++i) acc[i] = 0.f;

    const int c0 = cc * 64;
#pragma unroll 1
    for (int ch = 0; ch < 64; ch += 4) {
        __syncthreads();
        for (int t = tid; t < 4 * 324; t += 256) {
            int c = t / 324, p = t - c * 324;
            int yy = p / 18, xx = p - yy * 18;
            int gy = ty0 - 1 + yy, gx = tx0 - 1 + xx;
            float v = 0.f;
            if ((unsigned)gy < 64u && (unsigned)gx < 64u)
                v = x[(((b * CIN) + (c0 + ch + c)) << 12) + (gy << 6) + gx];
            xs[c][p] = v;
        }
        __syncthreads();
#pragma unroll 1
        for (int c = 0; c < 4; ++c) {
            const int cg = c0 + ch + c;   // wave-uniform -> scalar loads of w_off
#pragma unroll
            for (int tap = 0; tap < 9; ++tap) {
                const int dy = tap / 3, dx = tap % 3;
                float xv = xs[c][(tyl + dy) * 18 + (txl + dx)];
#pragma unroll
                for (int ko = 0; ko < 27; ++ko)
                    acc[ko] += xv * w_off[(ko * CIN + cg) * 9 + tap];
            }
        }
    }
    const int h = ty0 + tyl, w = tx0 + txl;
    const int base = ((cc * BB + b) * 27) * 4096 + (h << 6) + w;
#pragma unroll
    for (int ko = 0; ko < 27; ++ko) om_part[base + ko * 4096] = acc[ko];
}

// ---------------------------------------------------------------------------
// Kernel 2: transpose w [O][C][9] -> wt [C*9][O]  (coalesced loads in main)
// ---------------------------------------------------------------------------
__global__ __launch_bounds__(256) void k_wt(const float* __restrict__ w,
                                            float* __restrict__ wt) {
    int i = blockIdx.x * 256 + threadIdx.x;   // 2304*256 total
    int o = i & 255;
    int ck = i >> 8;
    wt[i] = w[o * 2304 + ck];
}

// ---------------------------------------------------------------------------
// Kernel 3: deformable conv + bias + BN + ReLU.
// grid: (W/PX, H, B), block 256 (thread = output channel o)
// ---------------------------------------------------------------------------
__global__ __launch_bounds__(256) void k_deform_main(
    const float* __restrict__ x, const float* __restrict__ om_part,
    const float* __restrict__ b_off, const float* __restrict__ wt,
    const float* __restrict__ bias, const float* __restrict__ gamma,
    const float* __restrict__ beta, const float* __restrict__ rmean,
    const float* __restrict__ rvar, float* __restrict__ out) {

    const int w0  = blockIdx.x * PX;
    const int h   = blockIdx.y;
    const int b   = blockIdx.z;
    const int tid = threadIdx.x;

    __shared__ int4   sidx[KK * PX];     // 4 corner indices per (k,px)
    __shared__ float4 swgt[KK * PX];     // 4 corner weights (incl. mask)
    __shared__ float  smp[8 * KK * PX];  // sampled [c][k][px]

    // ---- stage 0: per-(k,px) bilinear params (sum 4 offset-conv partials) --
    for (int j = tid; j < KK * PX; j += 256) {
        const int k  = j >> 5;     // /PX
        const int px = j & 31;
        const int w  = w0 + px;
        const int sp = (h << 6) + w;
        float oy = b_off[k], ox = b_off[k + KK], mz = b_off[k + 2 * KK];
#pragma unroll
        for (int q = 0; q < 4; ++q) {
            const float* basep = om_part + ((q * BB + b) * 27) * 4096 + sp;
            oy += basep[k * 4096];
            ox += basep[(k + KK) * 4096];
            mz += basep[(k + 2 * KK) * 4096];
        }
        const float mask = 1.f / (1.f + expf(-mz));
        const float ki = (float)(k / 3), kj = (float)(k % 3);
        const float py  = (float)h - 1.f + ki + oy;
        const float pxc = (float)w - 1.f + kj + ox;
        const float y0f = floorf(py), x0f = floorf(pxc);
        const float ly = py - y0f, lx = pxc - x0f;
        const int y0 = (int)y0f, x0 = (int)x0f;

        int4 id; float4 wg;
        {   // (y0, x0)
            int yi = y0, xi = x0;
            bool v = (yi >= 0) && (yi < HH) && (xi >= 0) && (xi < WWD);
            id.x = (min(max(yi, 0), HH - 1) << 6) + min(max(xi, 0), WWD - 1);
            wg.x = v ? (1.f - ly) * (1.f - lx) * mask : 0.f;
        }
        {   // (y0, x0+1)
            int yi = y0, xi = x0 + 1;
            bool v = (yi >= 0) && (yi < HH) && (xi >= 0) && (xi < WWD);
            id.y = (min(max(yi, 0), HH - 1) << 6) + min(max(xi, 0), WWD - 1);
            wg.y = v ? (1.f - ly) * lx * mask : 0.f;
        }
        {   // (y0+1, x0)
            int yi = y0 + 1, xi = x0;
            bool v = (yi >= 0) && (yi < HH) && (xi >= 0) && (xi < WWD);
            id.z = (min(max(yi, 0), HH - 1) << 6) + min(max(xi, 0), WWD - 1);
            wg.z = v ? ly * (1.f - lx) * mask : 0.f;
        }
        {   // (y0+1, x0+1)
            int yi = y0 + 1, xi = x0 + 1;
            bool v = (yi >= 0) && (yi < HH) && (xi >= 0) && (xi < WWD);
            id.w = (min(max(yi, 0), HH - 1) << 6) + min(max(xi, 0), WWD - 1);
            wg.w = v ? ly * lx * mask : 0.f;
        }
        sidx[j] = id;
        swgt[j] = wg;
    }
    __syncthreads();

    float acc[PX];
#pragma unroll
    for (int p = 0; p < PX; ++p) acc[p] = 0.f;

    // ---- main loop over input channels in chunks of 8 ----------------------
#pragma unroll 1
    for (int c0 = 0; c0 < CIN; c0 += 8) {
        // gather: 8*288 = 2304 sampled values, 9 per thread
        for (int t = tid; t < 8 * KK * PX; t += 256) {
            int c = t / (KK * PX);
            int j = t - c * (KK * PX);
            int4 id = sidx[j];
            float4 wg = swgt[j];
            const float* xb = x + (((b * CIN) + c0 + c) << 12);
            smp[t] = wg.x * xb[id.x] + wg.y * xb[id.y] +
                     wg.z * xb[id.z] + wg.w * xb[id.w];
        }
        __syncthreads();

        const float* wrow = wt + c0 * 9 * 256 + tid;
#pragma unroll 4
        for (int ck = 0; ck < 72; ++ck) {
            const float wv = wrow[ck * 256];          // coalesced across lanes
            const float4* sp4 = (const float4*)&smp[ck * PX];
#pragma unroll
            for (int p4 = 0; p4 < PX / 4; ++p4) {
                float4 s4 = sp4[p4];                  // LDS broadcast read
                acc[p4 * 4 + 0] += wv * s4.x;
                acc[p4 * 4 + 1] += wv * s4.y;
                acc[p4 * 4 + 2] += wv * s4.z;
                acc[p4 * 4 + 3] += wv * s4.w;
            }
        }
        __syncthreads();
    }

    // ---- epilogue: bias + BN + ReLU, float4 stores -------------------------
    const float bo  = bias[tid];
    const float inv = gamma[tid] * rsqrtf(rvar[tid] + 1e-5f);
    const float sh  = beta[tid] - rmean[tid] * inv;
    float* op = out + (((b * OUTC) + tid) << 12) + (h << 6) + w0;
#pragma unroll
    for (int p4 = 0; p4 < PX / 4; ++p4) {
        float4 v;
        v.x = fmaxf((acc[p4 * 4 + 0] + bo) * inv + sh, 0.f);
        v.y = fmaxf((acc[p4 * 4 + 1] + bo) * inv + sh, 0.f);
        v.z = fmaxf((acc[p4 * 4 + 2] + bo) * inv + sh, 0.f);
        v.w = fmaxf((acc[p4 * 4 + 3] + bo) * inv + sh, 0.f);
        ((float4*)op)[p4] = v;
    }
}

// ---------------------------------------------------------------------------
extern "C" void kernel_launch(void* const* d_in, const int* in_sizes, int n_in,
                              void* d_out, int out_size, void* d_ws, size_t ws_size,
                              hipStream_t stream) {
    const float* x     = (const float*)d_in[0];
    const float* w_off = (const float*)d_in[1];
    const float* b_off = (const float*)d_in[2];
    const float* w     = (const float*)d_in[3];
    const float* bias  = (const float*)d_in[4];
    const float* gamma = (const float*)d_in[5];
    const float* beta  = (const float*)d_in[6];
    const float* rmean = (const float*)d_in[7];
    const float* rvar  = (const float*)d_in[8];
    float* out = (float*)d_out;

    float* om_part = (float*)d_ws;                       // 4*4*27*4096 floats
    float* wt      = om_part + 4 * BB * 27 * 4096;       // 2304*256 floats

    dim3 gA(16, BB, 4);
    k_off_partial<<<gA, 256, 0, stream>>>(x, w_off, om_part);
    k_wt<<<2304, 256, 0, stream>>>(w, wt);
    dim3 gB(WWD / PX, HH, BB);
    k_deform_main<<<gB, 256, 0, stream>>>(x, om_part, b_off, wt, bias, gamma,
                                          beta, rmean, rvar, out);
}

// Round 6
// 431.785 us; speedup vs baseline: 1.8089x; 1.8089x over previous
//
#include <hip/hip_runtime.h>

#define HH 64
#define WWD 64
#define CIN 256
#define OUTC 256
#define BB 4
#define KK 9
#define NS 72   // K-steps: 9 taps * 8 channel-chunks of 32

typedef __attribute__((ext_vector_type(8))) short short8;
typedef __attribute__((ext_vector_type(4))) float float4v;

__device__ __forceinline__ short f2bf(float f) {
    unsigned u = __builtin_bit_cast(unsigned, f);
    u += 0x7fffu + ((u >> 16) & 1u);          // round-to-nearest-even
    return (short)(u >> 16);
}

// ---------------------------------------------------------------------------
// Kernel 1: offset conv (27 out ch), 8-way channel split -> 512 blocks.
// grid: (16 tiles of 16x16, B, 8), block 256
// ---------------------------------------------------------------------------
__global__ __launch_bounds__(256) void k_off_partial(const float* __restrict__ x,
                                                     const float* __restrict__ w_off,
                                                     float* __restrict__ om_part) {
    const int tile = blockIdx.x;
    const int b    = blockIdx.y;
    const int cc   = blockIdx.z;
    const int ty0 = (tile >> 2) << 4;
    const int tx0 = (tile & 3) << 4;
    const int tid = threadIdx.x;
    const int tyl = tid >> 4;
    const int txl = tid & 15;

    __shared__ float xs[4][18 * 18];

    float acc[27];
#pragma unroll
    for (int i = 0; i < 27; ++i) acc[i] = 0.f;

    const int c0 = cc * 32;
#pragma unroll 1
    for (int ch = 0; ch < 32; ch += 4) {
        __syncthreads();
        for (int t = tid; t < 4 * 324; t += 256) {
            int c = t / 324, p = t - c * 324;
            int yy = p / 18, xx = p - yy * 18;
            int gy = ty0 - 1 + yy, gx = tx0 - 1 + xx;
            float v = 0.f;
            if ((unsigned)gy < 64u && (unsigned)gx < 64u)
                v = x[(((b * CIN) + (c0 + ch + c)) << 12) + (gy << 6) + gx];
            xs[c][p] = v;
        }
        __syncthreads();
#pragma unroll 1
        for (int c = 0; c < 4; ++c) {
            const int cg = c0 + ch + c;   // wave-uniform -> scalar loads of w_off
#pragma unroll
            for (int tap = 0; tap < 9; ++tap) {
                const int dy = tap / 3, dx = tap % 3;
                float xv = xs[c][(tyl + dy) * 18 + (txl + dx)];
#pragma unroll
                for (int ko = 0; ko < 27; ++ko)
                    acc[ko] += xv * w_off[(ko * CIN + cg) * 9 + tap];
            }
        }
    }
    const int h = ty0 + tyl, w = tx0 + txl;
    const int base = ((cc * BB + b) * 27) * 4096 + (h << 6) + w;
#pragma unroll
    for (int ko = 0; ko < 27; ++ko) om_part[base + ko * 4096] = acc[ko];
}

// ---------------------------------------------------------------------------
// Kernel 2: pack weights to bf16, tap-major K, MFMA A-frag friendly:
// wt2[s][o][kk]  (s=0..71: tap=s>>3, c=(s&7)*32+kk)
// ---------------------------------------------------------------------------
__global__ __launch_bounds__(256) void k_pack(const float* __restrict__ w,
                                              short* __restrict__ wt2) {
    int gid = blockIdx.x * 256 + threadIdx.x;   // < 72*256*32
    int kk = gid & 31;
    int o  = (gid >> 5) & 255;
    int s  = gid >> 13;
    int tap = s >> 3;
    int c   = ((s & 7) << 5) + kk;
    wt2[gid] = f2bf(w[(o * CIN + c) * 9 + tap]);
}

// ---------------------------------------------------------------------------
// Kernel 3: deformable conv via bf16 MFMA + bias/BN/ReLU.
// grid: (2 M-halves, H, B), block 256 (4 waves).
// Block tile: M=128 outs x N=64 px, K=2304 in 72 steps of 32.
// ---------------------------------------------------------------------------
__global__ __launch_bounds__(256) void k_main(
    const float* __restrict__ x, const float* __restrict__ om_part,
    const float* __restrict__ b_off, const short* __restrict__ wt2,
    const float* __restrict__ bias, const float* __restrict__ gamma,
    const float* __restrict__ beta, const float* __restrict__ rmean,
    const float* __restrict__ rvar, float* __restrict__ out) {

    const int mhalf = blockIdx.x;
    const int h     = blockIdx.y;
    const int b     = blockIdx.z;
    const int tid   = threadIdx.x;
    const int lane  = tid & 63;
    const int wid   = tid >> 6;

    __shared__ int4   sidx[KK * 64];
    __shared__ float4 swgt[KK * 64];
    __shared__ short  S[2][4][64][8];    // [buf][kgroup][px][8 k] bf16
    __shared__ float  sInv[128], sSh[128];

    // ---- stage 0: bilinear params per (tap,px); BN consts ------------------
    for (int j = tid; j < KK * 64; j += 256) {
        const int k  = j >> 6;
        const int px = j & 63;
        const int sp = (h << 6) + px;
        float oy = b_off[k], ox = b_off[k + KK], mz = b_off[k + 2 * KK];
#pragma unroll
        for (int q = 0; q < 8; ++q) {
            const float* bp = om_part + (size_t)((q * BB + b) * 27) * 4096 + sp;
            oy += bp[k * 4096];
            ox += bp[(k + KK) * 4096];
            mz += bp[(k + 2 * KK) * 4096];
        }
        const float mask = 1.f / (1.f + expf(-mz));
        const float py  = (float)h  - 1.f + (float)(k / 3) + oy;
        const float pxc = (float)px - 1.f + (float)(k % 3) + ox;
        const float y0f = floorf(py), x0f = floorf(pxc);
        const float ly = py - y0f, lx = pxc - x0f;
        const int y0 = (int)y0f, x0 = (int)x0f;

        int4 id; float4 wg;
        {
            int yi = y0, xi = x0;
            bool v = (yi >= 0) && (yi < HH) && (xi >= 0) && (xi < WWD);
            id.x = (min(max(yi, 0), HH - 1) << 6) + min(max(xi, 0), WWD - 1);
            wg.x = v ? (1.f - ly) * (1.f - lx) * mask : 0.f;
        }
        {
            int yi = y0, xi = x0 + 1;
            bool v = (yi >= 0) && (yi < HH) && (xi >= 0) && (xi < WWD);
            id.y = (min(max(yi, 0), HH - 1) << 6) + min(max(xi, 0), WWD - 1);
            wg.y = v ? (1.f - ly) * lx * mask : 0.f;
        }
        {
            int yi = y0 + 1, xi = x0;
            bool v = (yi >= 0) && (yi < HH) && (xi >= 0) && (xi < WWD);
            id.z = (min(max(yi, 0), HH - 1) << 6) + min(max(xi, 0), WWD - 1);
            wg.z = v ? ly * (1.f - lx) * mask : 0.f;
        }
        {
            int yi = y0 + 1, xi = x0 + 1;
            bool v = (yi >= 0) && (yi < HH) && (xi >= 0) && (xi < WWD);
            id.w = (min(max(yi, 0), HH - 1) << 6) + min(max(xi, 0), WWD - 1);
            wg.w = v ? ly * lx * mask : 0.f;
        }
        sidx[j] = id;
        swgt[j] = wg;
    }
    if (tid < 128) {
        const int o = mhalf * 128 + tid;
        const float inv = gamma[o] * rsqrtf(rvar[o] + 1e-5f);
        sInv[tid] = inv;
        sSh[tid]  = beta[o] - rmean[o] * inv + bias[o] * inv;
    }

    const int px_t = tid & 63;
    const int cl0  = tid >> 6;            // k-group this thread fills
    const float* xb = x + ((size_t)b << 20);

    float g0[8], g1[8], g2[8], g3[8];     // pending gather results
    int4 idP; float4 wgP;

    auto ISSUE = [&](int s2) {
        const int tap = s2 >> 3;
        idP = sidx[tap * 64 + px_t];
        wgP = swgt[tap * 64 + px_t];
        const float* xc = xb + ((((s2 & 7) << 5) + cl0 * 8) << 12);
#pragma unroll
        for (int j2 = 0; j2 < 8; ++j2) {
            g0[j2] = xc[idP.x];
            g1[j2] = xc[idP.y];
            g2[j2] = xc[idP.z];
            g3[j2] = xc[idP.w];
            xc += 4096;
        }
    };
    auto CONSUME = [&](int buf) {
        short8 p;
#pragma unroll
        for (int j2 = 0; j2 < 8; ++j2) {
            float v = g0[j2] * wgP.x + g1[j2] * wgP.y +
                      g2[j2] * wgP.z + g3[j2] * wgP.w;
            p[j2] = f2bf(v);
        }
        *(short8*)(&S[buf][cl0][px_t][0]) = p;
    };

    // A-frag base: lane holds row o = base+(lane&15), k = (lane>>4)*8+j
    const short* wbase = wt2 + ((mhalf * 128 + wid * 32 + (lane & 15)) << 5)
                             + ((lane >> 4) << 3);
    const int bpx = lane & 15;
    const int bg  = lane >> 4;

    float4v acc[2][4];
#pragma unroll
    for (int mt = 0; mt < 2; ++mt)
#pragma unroll
        for (int nt = 0; nt < 4; ++nt) acc[mt][nt] = (float4v){0.f, 0.f, 0.f, 0.f};

    __syncthreads();             // stage-0 LDS ready

    // ---- pipeline prologue -------------------------------------------------
    ISSUE(0);
    CONSUME(0);
    ISSUE(1);
    short8 aC0 = *(const short8*)(wbase);
    short8 aC1 = *(const short8*)(wbase + 512);
    __syncthreads();             // S[0] written

    // ---- K loop ------------------------------------------------------------
#pragma unroll 1
    for (int s = 0; s < NS; ++s) {
        const int sn = (s + 1 < NS) ? (s + 1) : s;
        short8 aN0 = *(const short8*)(wbase + (size_t)sn * 8192);
        short8 aN1 = *(const short8*)(wbase + (size_t)sn * 8192 + 512);

        const int buf = s & 1;
        short8 b0 = *(const short8*)(&S[buf][bg][ 0 + bpx][0]);
        short8 b1 = *(const short8*)(&S[buf][bg][16 + bpx][0]);
        short8 b2 = *(const short8*)(&S[buf][bg][32 + bpx][0]);
        short8 b3 = *(const short8*)(&S[buf][bg][48 + bpx][0]);

        acc[0][0] = __builtin_amdgcn_mfma_f32_16x16x32_bf16(aC0, b0, acc[0][0], 0, 0, 0);
        acc[0][1] = __builtin_amdgcn_mfma_f32_16x16x32_bf16(aC0, b1, acc[0][1], 0, 0, 0);
        acc[0][2] = __builtin_amdgcn_mfma_f32_16x16x32_bf16(aC0, b2, acc[0][2], 0, 0, 0);
        acc[0][3] = __builtin_amdgcn_mfma_f32_16x16x32_bf16(aC0, b3, acc[0][3], 0, 0, 0);
        acc[1][0] = __builtin_amdgcn_mfma_f32_16x16x32_bf16(aC1, b0, acc[1][0], 0, 0, 0);
        acc[1][1] = __builtin_amdgcn_mfma_f32_16x16x32_bf16(aC1, b1, acc[1][1], 0, 0, 0);
        acc[1][2] = __builtin_amdgcn_mfma_f32_16x16x32_bf16(aC1, b2, acc[1][2], 0, 0, 0);
        acc[1][3] = __builtin_amdgcn_mfma_f32_16x16x32_bf16(aC1, b3, acc[1][3], 0, 0, 0);

        if (s < NS - 1) {
            CONSUME((s + 1) & 1);          // waits on gathers issued last iter
            if (s + 2 < NS) ISSUE(s + 2);  // gathers in flight across barrier
        }
        aC0 = aN0; aC1 = aN1;
        __syncthreads();
    }

    // ---- epilogue: BN+ReLU, D layout col=lane&15, row=(lane>>4)*4+r --------
    const int r4 = lane >> 4;
    float* ob = out + (((size_t)b * 256 + mhalf * 128) << 12) + (h << 6);
#pragma unroll
    for (int mt = 0; mt < 2; ++mt)
#pragma unroll
        for (int nt = 0; nt < 4; ++nt) {
            const int px = nt * 16 + bpx;
#pragma unroll
            for (int r = 0; r < 4; ++r) {
                const int oloc = wid * 32 + mt * 16 + r4 * 4 + r;
                const float v = acc[mt][nt][r] * sInv[oloc] + sSh[oloc];
                ob[((size_t)oloc << 12) + px] = fmaxf(v, 0.f);
            }
        }
}

// ---------------------------------------------------------------------------
extern "C" void kernel_launch(void* const* d_in, const int* in_sizes, int n_in,
                              void* d_out, int out_size, void* d_ws, size_t ws_size,
                              hipStream_t stream) {
    const float* x     = (const float*)d_in[0];
    const float* w_off = (const float*)d_in[1];
    const float* b_off = (const float*)d_in[2];
    const float* w     = (const float*)d_in[3];
    const float* bias  = (const float*)d_in[4];
    const float* gamma = (const float*)d_in[5];
    const float* beta  = (const float*)d_in[6];
    const float* rmean = (const float*)d_in[7];
    const float* rvar  = (const float*)d_in[8];
    float* out = (float*)d_out;

    float* om_part = (float*)d_ws;                     // 8*4*27*4096 floats
    short* wt2     = (short*)(om_part + 8 * BB * 27 * 4096);  // 72*256*32 bf16

    dim3 gA(16, BB, 8);
    k_off_partial<<<gA, 256, 0, stream>>>(x, w_off, om_part);
    k_pack<<<2304, 256, 0, stream>>>(w, wt2);
    dim3 gB(2, HH, BB);
    k_main<<<gB, 256, 0, stream>>>(x, om_part, b_off, wt2, bias, gamma,
                                   beta, rmean, rvar, out);
}

// Round 7
// 237.917 us; speedup vs baseline: 3.2829x; 1.8149x over previous
//
#include <hip/hip_runtime.h>

#define HH 64
#define WWD 64
#define CIN 256
#define OUTC 256
#define BB 4
#define KK 9
#define NS 72    // main-kernel K-steps: 9 taps * 8 chunks of 32
#define NSO 36   // offset-conv K-steps per q-half
#define QQ 2     // offset-conv K-split partials

typedef __attribute__((ext_vector_type(8))) short short8;
typedef __attribute__((ext_vector_type(4))) float float4v;

__device__ __forceinline__ short f2bf(float f) {
    unsigned u = __builtin_bit_cast(unsigned, f);
    u += 0x7fffu + ((u >> 16) & 1u);          // round-to-nearest-even
    return (short)(u >> 16);
}

// ---------------------------------------------------------------------------
// Kernel P1: pack main-conv weights bf16, tap-major K: wt2[s][o 256][kk 32]
// ---------------------------------------------------------------------------
__global__ __launch_bounds__(256) void k_pack(const float* __restrict__ w,
                                              short* __restrict__ wt2) {
    int gid = blockIdx.x * 256 + threadIdx.x;   // < 72*256*32
    int kk = gid & 31;
    int o  = (gid >> 5) & 255;
    int s  = gid >> 13;
    int tap = s >> 3;
    int c   = ((s & 7) << 5) + kk;
    wt2[gid] = f2bf(w[(o * CIN + c) * 9 + tap]);
}

// ---------------------------------------------------------------------------
// Kernel P2: pack offset-conv weights bf16: wo2[s][m 32][kk 32], rows 27..31=0
// ---------------------------------------------------------------------------
__global__ __launch_bounds__(256) void k_pack_off(const float* __restrict__ w_off,
                                                  short* __restrict__ wo2) {
    int gid = blockIdx.x * 256 + threadIdx.x;   // < 72*32*32 = 73728
    int kk = gid & 31;
    int m  = (gid >> 5) & 31;
    int s  = gid >> 10;
    int tap = s >> 3;
    int c   = ((s & 7) << 5) + kk;
    wo2[gid] = (m < 27) ? f2bf(w_off[(m * CIN + c) * 9 + tap]) : (short)0;
}

// ---------------------------------------------------------------------------
// Kernel 1: offset conv via bf16 MFMA. grid (H, B, QQ), block 256 (4 waves).
// Tile: M=32 (27 outs), N=64 px (one row), K=1152 per q (36 steps of 32).
// B staging: no gather — contiguous x-row loads, zero-padded at borders.
// ---------------------------------------------------------------------------
__global__ __launch_bounds__(256) void k_off_mfma(const float* __restrict__ x,
                                                  const short* __restrict__ wo2,
                                                  float* __restrict__ om_part) {
    const int h   = blockIdx.x;
    const int b   = blockIdx.y;
    const int q   = blockIdx.z;
    const int tid = threadIdx.x;
    const int lane = tid & 63;
    const int wid  = tid >> 6;

    __shared__ short S[2][4][64][8];   // [buf][kgroup][px][8 k] bf16

    const int px_t = tid & 63;
    const int g    = tid >> 6;
    const float* xb = x + ((size_t)b << 20);

    float gv[8];
    auto ISSUE = [&](int s2) {
        const int tap = s2 >> 3;
        const int cc  = s2 & 7;
        const int gy = h + tap / 3 - 1;
        const int gx = px_t + tap % 3 - 1;
        const bool ok = ((unsigned)gy < 64u) && ((unsigned)gx < 64u);
        const float* xc = xb + (((cc << 5) + (g << 3)) << 12) + (gy << 6) + gx;
#pragma unroll
        for (int j = 0; j < 8; ++j)
            gv[j] = ok ? xc[(size_t)j << 12] : 0.f;
    };
    auto CONSUME = [&](int buf) {
        short8 p;
#pragma unroll
        for (int j = 0; j < 8; ++j) p[j] = f2bf(gv[j]);
        *(short8*)(&S[buf][g][px_t][0]) = p;
    };

    const int arow = lane & 15;        // A row within 16-tile
    const int akk  = (lane >> 4) << 3; // A k start
    const int bpx  = lane & 15;
    const int bg   = lane >> 4;

    float4v acc0 = {0.f, 0.f, 0.f, 0.f};
    float4v acc1 = {0.f, 0.f, 0.f, 0.f};

    const int s0 = q * NSO;
    ISSUE(s0); CONSUME(0); ISSUE(s0 + 1);
    const short* abase = wo2 + (size_t)s0 * 1024 + arow * 32 + akk;
    short8 aC0 = *(const short8*)(abase);
    short8 aC1 = *(const short8*)(abase + 512);      // mt=1: +16 rows
    __syncthreads();

#pragma unroll 1
    for (int ls = 0; ls < NSO; ++ls) {
        const int lsn = (ls + 1 < NSO) ? ls + 1 : ls;
        const short* an = wo2 + (size_t)(s0 + lsn) * 1024 + arow * 32 + akk;
        short8 aN0 = *(const short8*)(an);
        short8 aN1 = *(const short8*)(an + 512);

        short8 bf = *(const short8*)(&S[ls & 1][bg][(wid << 4) + bpx][0]);
        acc0 = __builtin_amdgcn_mfma_f32_16x16x32_bf16(aC0, bf, acc0, 0, 0, 0);
        acc1 = __builtin_amdgcn_mfma_f32_16x16x32_bf16(aC1, bf, acc1, 0, 0, 0);

        if (ls < NSO - 1) {
            CONSUME((ls + 1) & 1);
            if (ls + 2 < NSO) ISSUE(s0 + ls + 2);
        }
        aC0 = aN0; aC1 = aN1;
        __syncthreads();
    }

    // D layout: col=lane&15 (px), row=(lane>>4)*4+r
    const int pxo = (wid << 4) + bpx;
    float* ob = om_part + (((size_t)(q * BB + b) * 27) << 12) + (h << 6) + pxo;
#pragma unroll
    for (int r = 0; r < 4; ++r) {
        const int m0 = ((lane >> 4) << 2) + r;       // 0..15
        ob[(size_t)m0 << 12] = acc0[r];
        const int m1 = 16 + m0;                      // 16..31
        if (m1 < 27) ob[(size_t)m1 << 12] = acc1[r];
    }
}

// ---------------------------------------------------------------------------
// Kernel 2: deformable conv via bf16 MFMA + bias/BN/ReLU.
// grid: (2 M-halves, H, B), block 256 (4 waves).
// ---------------------------------------------------------------------------
__global__ __launch_bounds__(256) void k_main(
    const float* __restrict__ x, const float* __restrict__ om_part,
    const float* __restrict__ b_off, const short* __restrict__ wt2,
    const float* __restrict__ bias, const float* __restrict__ gamma,
    const float* __restrict__ beta, const float* __restrict__ rmean,
    const float* __restrict__ rvar, float* __restrict__ out) {

    const int mhalf = blockIdx.x;
    const int h     = blockIdx.y;
    const int b     = blockIdx.z;
    const int tid   = threadIdx.x;
    const int lane  = tid & 63;
    const int wid   = tid >> 6;

    __shared__ int4   sidx[KK * 64];
    __shared__ float4 swgt[KK * 64];
    __shared__ short  S[2][4][64][8];    // [buf][kgroup][px][8 k] bf16
    __shared__ float  sInv[128], sSh[128];

    // ---- stage 0: bilinear params per (tap,px); BN consts ------------------
    for (int j = tid; j < KK * 64; j += 256) {
        const int k  = j >> 6;
        const int px = j & 63;
        const int sp = (h << 6) + px;
        float oy = b_off[k], ox = b_off[k + KK], mz = b_off[k + 2 * KK];
#pragma unroll
        for (int q = 0; q < QQ; ++q) {
            const float* bp = om_part + (size_t)((q * BB + b) * 27) * 4096 + sp;
            oy += bp[k * 4096];
            ox += bp[(k + KK) * 4096];
            mz += bp[(k + 2 * KK) * 4096];
        }
        const float mask = 1.f / (1.f + expf(-mz));
        const float py  = (float)h  - 1.f + (float)(k / 3) + oy;
        const float pxc = (float)px - 1.f + (float)(k % 3) + ox;
        const float y0f = floorf(py), x0f = floorf(pxc);
        const float ly = py - y0f, lx = pxc - x0f;
        const int y0 = (int)y0f, x0 = (int)x0f;

        int4 id; float4 wg;
        {
            int yi = y0, xi = x0;
            bool v = (yi >= 0) && (yi < HH) && (xi >= 0) && (xi < WWD);
            id.x = (min(max(yi, 0), HH - 1) << 6) + min(max(xi, 0), WWD - 1);
            wg.x = v ? (1.f - ly) * (1.f - lx) * mask : 0.f;
        }
        {
            int yi = y0, xi = x0 + 1;
            bool v = (yi >= 0) && (yi < HH) && (xi >= 0) && (xi < WWD);
            id.y = (min(max(yi, 0), HH - 1) << 6) + min(max(xi, 0), WWD - 1);
            wg.y = v ? (1.f - ly) * lx * mask : 0.f;
        }
        {
            int yi = y0 + 1, xi = x0;
            bool v = (yi >= 0) && (yi < HH) && (xi >= 0) && (xi < WWD);
            id.z = (min(max(yi, 0), HH - 1) << 6) + min(max(xi, 0), WWD - 1);
            wg.z = v ? ly * (1.f - lx) * mask : 0.f;
        }
        {
            int yi = y0 + 1, xi = x0 + 1;
            bool v = (yi >= 0) && (yi < HH) && (xi >= 0) && (xi < WWD);
            id.w = (min(max(yi, 0), HH - 1) << 6) + min(max(xi, 0), WWD - 1);
            wg.w = v ? ly * lx * mask : 0.f;
        }
        sidx[j] = id;
        swgt[j] = wg;
    }
    if (tid < 128) {
        const int o = mhalf * 128 + tid;
        const float inv = gamma[o] * rsqrtf(rvar[o] + 1e-5f);
        sInv[tid] = inv;
        sSh[tid]  = beta[o] - rmean[o] * inv + bias[o] * inv;
    }

    const int px_t = tid & 63;
    const int cl0  = tid >> 6;            // k-group this thread fills
    const float* xb = x + ((size_t)b << 20);

    float g0[8], g1[8], g2[8], g3[8];     // pending gather results
    int4 idP; float4 wgP;

    auto ISSUE = [&](int s2) {
        const int tap = s2 >> 3;
        idP = sidx[tap * 64 + px_t];
        wgP = swgt[tap * 64 + px_t];
        const float* xc = xb + ((((s2 & 7) << 5) + cl0 * 8) << 12);
#pragma unroll
        for (int j2 = 0; j2 < 8; ++j2) {
            g0[j2] = xc[idP.x];
            g1[j2] = xc[idP.y];
            g2[j2] = xc[idP.z];
            g3[j2] = xc[idP.w];
            xc += 4096;
        }
    };
    auto CONSUME = [&](int buf) {
        short8 p;
#pragma unroll
        for (int j2 = 0; j2 < 8; ++j2) {
            float v = g0[j2] * wgP.x + g1[j2] * wgP.y +
                      g2[j2] * wgP.z + g3[j2] * wgP.w;
            p[j2] = f2bf(v);
        }
        *(short8*)(&S[buf][cl0][px_t][0]) = p;
    };

    // A-frag base: lane holds row o = base+(lane&15), k = (lane>>4)*8+j
    const short* wbase = wt2 + ((mhalf * 128 + wid * 32 + (lane & 15)) << 5)
                             + ((lane >> 4) << 3);
    const int bpx = lane & 15;
    const int bg  = lane >> 4;

    float4v acc[2][4];
#pragma unroll
    for (int mt = 0; mt < 2; ++mt)
#pragma unroll
        for (int nt = 0; nt < 4; ++nt) acc[mt][nt] = (float4v){0.f, 0.f, 0.f, 0.f};

    __syncthreads();             // stage-0 LDS ready

    // ---- pipeline prologue -------------------------------------------------
    ISSUE(0);
    CONSUME(0);
    ISSUE(1);
    short8 aC0 = *(const short8*)(wbase);
    short8 aC1 = *(const short8*)(wbase + 512);
    __syncthreads();             // S[0] written

    // ---- K loop ------------------------------------------------------------
#pragma unroll 1
    for (int s = 0; s < NS; ++s) {
        const int sn = (s + 1 < NS) ? (s + 1) : s;
        short8 aN0 = *(const short8*)(wbase + (size_t)sn * 8192);
        short8 aN1 = *(const short8*)(wbase + (size_t)sn * 8192 + 512);

        const int buf = s & 1;
        short8 b0 = *(const short8*)(&S[buf][bg][ 0 + bpx][0]);
        short8 b1 = *(const short8*)(&S[buf][bg][16 + bpx][0]);
        short8 b2 = *(const short8*)(&S[buf][bg][32 + bpx][0]);
        short8 b3 = *(const short8*)(&S[buf][bg][48 + bpx][0]);

        acc[0][0] = __builtin_amdgcn_mfma_f32_16x16x32_bf16(aC0, b0, acc[0][0], 0, 0, 0);
        acc[0][1] = __builtin_amdgcn_mfma_f32_16x16x32_bf16(aC0, b1, acc[0][1], 0, 0, 0);
        acc[0][2] = __builtin_amdgcn_mfma_f32_16x16x32_bf16(aC0, b2, acc[0][2], 0, 0, 0);
        acc[0][3] = __builtin_amdgcn_mfma_f32_16x16x32_bf16(aC0, b3, acc[0][3], 0, 0, 0);
        acc[1][0] = __builtin_amdgcn_mfma_f32_16x16x32_bf16(aC1, b0, acc[1][0], 0, 0, 0);
        acc[1][1] = __builtin_amdgcn_mfma_f32_16x16x32_bf16(aC1, b1, acc[1][1], 0, 0, 0);
        acc[1][2] = __builtin_amdgcn_mfma_f32_16x16x32_bf16(aC1, b2, acc[1][2], 0, 0, 0);
        acc[1][3] = __builtin_amdgcn_mfma_f32_16x16x32_bf16(aC1, b3, acc[1][3], 0, 0, 0);

        if (s < NS - 1) {
            CONSUME((s + 1) & 1);          // waits on gathers issued last iter
            if (s + 2 < NS) ISSUE(s + 2);  // gathers in flight across barrier
        }
        aC0 = aN0; aC1 = aN1;
        __syncthreads();
    }

    // ---- epilogue: BN+ReLU, D layout col=lane&15, row=(lane>>4)*4+r --------
    const int r4 = lane >> 4;
    float* ob = out + (((size_t)b * 256 + mhalf * 128) << 12) + (h << 6);
#pragma unroll
    for (int mt = 0; mt < 2; ++mt)
#pragma unroll
        for (int nt = 0; nt < 4; ++nt) {
            const int px = nt * 16 + bpx;
#pragma unroll
            for (int r = 0; r < 4; ++r) {
                const int oloc = wid * 32 + mt * 16 + r4 * 4 + r;
                const float v = acc[mt][nt][r] * sInv[oloc] + sSh[oloc];
                ob[((size_t)oloc << 12) + px] = fmaxf(v, 0.f);
            }
        }
}

// ---------------------------------------------------------------------------
extern "C" void kernel_launch(void* const* d_in, const int* in_sizes, int n_in,
                              void* d_out, int out_size, void* d_ws, size_t ws_size,
                              hipStream_t stream) {
    const float* x     = (const float*)d_in[0];
    const float* w_off = (const float*)d_in[1];
    const float* b_off = (const float*)d_in[2];
    const float* w     = (const float*)d_in[3];
    const float* bias  = (const float*)d_in[4];
    const float* gamma = (const float*)d_in[5];
    const float* beta  = (const float*)d_in[6];
    const float* rmean = (const float*)d_in[7];
    const float* rvar  = (const float*)d_in[8];
    float* out = (float*)d_out;

    float* om_part = (float*)d_ws;                          // QQ*4*27*4096 f32
    short* wt2     = (short*)(om_part + QQ * BB * 27 * 4096); // 72*256*32 bf16
    short* wo2     = wt2 + 72 * 256 * 32;                     // 72*32*32 bf16

    k_pack<<<2304, 256, 0, stream>>>(w, wt2);
    k_pack_off<<<288, 256, 0, stream>>>(w_off, wo2);
    dim3 gO(HH, BB, QQ);
    k_off_mfma<<<gO, 256, 0, stream>>>(x, wo2, om_part);
    dim3 gB(2, HH, BB);
    k_main<<<gB, 256, 0, stream>>>(x, om_part, b_off, wt2, bias, gamma,
                                   beta, rmean, rvar, out);
}

// Round 8
// 234.545 us; speedup vs baseline: 3.3301x; 1.0144x over previous
//
#include <hip/hip_runtime.h>

#define HH 64
#define WWD 64
#define CIN 256
#define OUTC 256
#define BB 4
#define KK 9
#define NS 72    // main-kernel K-steps: 8 chunks * 9 taps (CHANNEL-major)
#define NSO 36   // offset-conv K-steps per q-half
#define QQ 2     // offset-conv K-split partials

typedef __attribute__((ext_vector_type(8))) short short8;
typedef __attribute__((ext_vector_type(4))) float float4v;

__device__ __forceinline__ short f2bf(float f) {
    unsigned u = __builtin_bit_cast(unsigned, f);
    u += 0x7fffu + ((u >> 16) & 1u);          // round-to-nearest-even
    return (short)(u >> 16);
}
// floor(s/9) for s in [0,72)
__device__ __forceinline__ int div9(int s) { return (s * 57) >> 9; }

// ---------------------------------------------------------------------------
// Kernel P1: pack main weights bf16, CHANNEL-major K: s=chunk*9+tap
// wt2[s][o 256][kk 32], c = chunk*32+kk
// ---------------------------------------------------------------------------
__global__ __launch_bounds__(256) void k_pack(const float* __restrict__ w,
                                              short* __restrict__ wt2) {
    int gid = blockIdx.x * 256 + threadIdx.x;   // < 72*256*32
    int kk = gid & 31;
    int o  = (gid >> 5) & 255;
    int s  = gid >> 13;
    int chunk = div9(s), tap = s - 9 * chunk;
    int c = (chunk << 5) + kk;
    wt2[gid] = f2bf(w[(o * CIN + c) * 9 + tap]);
}

// ---------------------------------------------------------------------------
// Kernel P2: pack offset weights bf16: wo2[s][m 32][kk 32], rows 27..31 = 0
// ---------------------------------------------------------------------------
__global__ __launch_bounds__(256) void k_pack_off(const float* __restrict__ w_off,
                                                  short* __restrict__ wo2) {
    int gid = blockIdx.x * 256 + threadIdx.x;   // < 72*32*32
    int kk = gid & 31;
    int m  = (gid >> 5) & 31;
    int s  = gid >> 10;
    int chunk = div9(s), tap = s - 9 * chunk;
    int c = (chunk << 5) + kk;
    wo2[gid] = (m < 27) ? f2bf(w_off[(m * CIN + c) * 9 + tap]) : (short)0;
}

// ---------------------------------------------------------------------------
// Kernel 1: offset conv via bf16 MFMA. flat grid 512, XCD-swizzled.
// Tile: M=32 (27 outs), N=64 px (one row), K=1152 per q (36 steps of 32).
// ---------------------------------------------------------------------------
__global__ __launch_bounds__(256) void k_off_mfma(const float* __restrict__ x,
                                                  const short* __restrict__ wo2,
                                                  float* __restrict__ om_part) {
    const int wgid = blockIdx.x;                       // 0..511
    const int swz  = ((wgid & 7) << 6) + (wgid >> 3);  // XCD-contiguous
    const int q = swz & 1;
    const int h = (swz >> 1) & 63;
    const int b = swz >> 7;
    const int tid = threadIdx.x;
    const int lane = tid & 63;
    const int wid  = tid >> 6;

    __shared__ short S[2][4][64][8];   // [buf][kgroup][px][8 k] bf16

    const int px_t = tid & 63;
    const int g    = tid >> 6;
    const float* xb = x + ((size_t)b << 20);

    float gv[8];
    auto ISSUE = [&](int s2) {
        const int chunk = div9(s2), tap = s2 - 9 * chunk;
        const int gy = h + tap / 3 - 1;
        const int gx = px_t + tap % 3 - 1;
        const bool ok = ((unsigned)gy < 64u) && ((unsigned)gx < 64u);
        const float* xc = xb + (((chunk << 5) + (g << 3)) << 12) + (gy << 6) + gx;
#pragma unroll
        for (int j = 0; j < 8; ++j)
            gv[j] = ok ? xc[(size_t)j << 12] : 0.f;
    };
    auto CONSUME = [&](int buf) {
        short8 p;
#pragma unroll
        for (int j = 0; j < 8; ++j) p[j] = f2bf(gv[j]);
        *(short8*)(&S[buf][g][px_t][0]) = p;
    };

    const int arow = lane & 15;
    const int akk  = (lane >> 4) << 3;
    const int bpx  = lane & 15;
    const int bg   = lane >> 4;

    float4v acc0 = {0.f, 0.f, 0.f, 0.f};
    float4v acc1 = {0.f, 0.f, 0.f, 0.f};

    const int s0 = q * NSO;
    ISSUE(s0); CONSUME(0); ISSUE(s0 + 1);
    const short* abase = wo2 + (size_t)s0 * 1024 + arow * 32 + akk;
    short8 aC0 = *(const short8*)(abase);
    short8 aC1 = *(const short8*)(abase + 512);
    __syncthreads();

#pragma unroll 1
    for (int ls = 0; ls < NSO; ++ls) {
        const int lsn = (ls + 1 < NSO) ? ls + 1 : ls;
        const short* an = wo2 + (size_t)(s0 + lsn) * 1024 + arow * 32 + akk;
        short8 aN0 = *(const short8*)(an);
        short8 aN1 = *(const short8*)(an + 512);

        short8 bf = *(const short8*)(&S[ls & 1][bg][(wid << 4) + bpx][0]);
        acc0 = __builtin_amdgcn_mfma_f32_16x16x32_bf16(aC0, bf, acc0, 0, 0, 0);
        acc1 = __builtin_amdgcn_mfma_f32_16x16x32_bf16(aC1, bf, acc1, 0, 0, 0);

        if (ls < NSO - 1) {
            CONSUME((ls + 1) & 1);
            if (ls + 2 < NSO) ISSUE(s0 + ls + 2);
        }
        aC0 = aN0; aC1 = aN1;
        __syncthreads();
    }

    // D layout: col=lane&15 (px), row=(lane>>4)*4+r
    const int pxo = (wid << 4) + bpx;
    float* ob = om_part + (((size_t)(q * BB + b) * 27) << 12) + (h << 6) + pxo;
#pragma unroll
    for (int r = 0; r < 4; ++r) {
        const int m0 = ((lane >> 4) << 2) + r;
        ob[(size_t)m0 << 12] = acc0[r];
        const int m1 = 16 + m0;
        if (m1 < 27) ob[(size_t)m1 << 12] = acc1[r];
    }
}

// ---------------------------------------------------------------------------
// Kernel 2: deformable conv via bf16 MFMA + bias/BN/ReLU.
// flat grid 512, XCD-swizzled; block 256 (4 waves), M=128 x N=64, K=2304.
// ---------------------------------------------------------------------------
__global__ __launch_bounds__(256) void k_main(
    const float* __restrict__ x, const float* __restrict__ om_part,
    const float* __restrict__ b_off, const short* __restrict__ wt2,
    const float* __restrict__ bias, const float* __restrict__ gamma,
    const float* __restrict__ beta, const float* __restrict__ rmean,
    const float* __restrict__ rvar, float* __restrict__ out) {

    const int wgid = blockIdx.x;                       // 0..511
    const int swz  = ((wgid & 7) << 6) + (wgid >> 3);  // XCD-contiguous
    const int mhalf = swz & 1;
    const int h     = (swz >> 1) & 63;
    const int b     = swz >> 7;
    const int tid   = threadIdx.x;
    const int lane  = tid & 63;
    const int wid   = tid >> 6;

    __shared__ int4   sidx[KK * 64];
    __shared__ float4 swgt[KK * 64];
    __shared__ short  S[2][4][64][8];    // [buf][kgroup][px][8 k] bf16
    __shared__ float  sInv[128], sSh[128];

    // ---- stage 0: bilinear params per (tap,px); BN consts ------------------
    for (int j = tid; j < KK * 64; j += 256) {
        const int k  = j >> 6;
        const int px = j & 63;
        const int sp = (h << 6) + px;
        float oy = b_off[k], ox = b_off[k + KK], mz = b_off[k + 2 * KK];
#pragma unroll
        for (int q = 0; q < QQ; ++q) {
            const float* bp = om_part + (size_t)((q * BB + b) * 27) * 4096 + sp;
            oy += bp[k * 4096];
            ox += bp[(k + KK) * 4096];
            mz += bp[(k + 2 * KK) * 4096];
        }
        const float mask = 1.f / (1.f + expf(-mz));
        const float py  = (float)h  - 1.f + (float)(k / 3) + oy;
        const float pxc = (float)px - 1.f + (float)(k % 3) + ox;
        const float y0f = floorf(py), x0f = floorf(pxc);
        const float ly = py - y0f, lx = pxc - x0f;
        const int y0 = (int)y0f, x0 = (int)x0f;

        int4 id; float4 wg;
        {
            int yi = y0, xi = x0;
            bool v = (yi >= 0) && (yi < HH) && (xi >= 0) && (xi < WWD);
            id.x = (min(max(yi, 0), HH - 1) << 6) + min(max(xi, 0), WWD - 1);
            wg.x = v ? (1.f - ly) * (1.f - lx) * mask : 0.f;
        }
        {
            int yi = y0, xi = x0 + 1;
            bool v = (yi >= 0) && (yi < HH) && (xi >= 0) && (xi < WWD);
            id.y = (min(max(yi, 0), HH - 1) << 6) + min(max(xi, 0), WWD - 1);
            wg.y = v ? (1.f - ly) * lx * mask : 0.f;
        }
        {
            int yi = y0 + 1, xi = x0;
            bool v = (yi >= 0) && (yi < HH) && (xi >= 0) && (xi < WWD);
            id.z = (min(max(yi, 0), HH - 1) << 6) + min(max(xi, 0), WWD - 1);
            wg.z = v ? ly * (1.f - lx) * mask : 0.f;
        }
        {
            int yi = y0 + 1, xi = x0 + 1;
            bool v = (yi >= 0) && (yi < HH) && (xi >= 0) && (xi < WWD);
            id.w = (min(max(yi, 0), HH - 1) << 6) + min(max(xi, 0), WWD - 1);
            wg.w = v ? ly * lx * mask : 0.f;
        }
        sidx[j] = id;
        swgt[j] = wg;
    }
    if (tid < 128) {
        const int o = mhalf * 128 + tid;
        const float inv = gamma[o] * rsqrtf(rvar[o] + 1e-5f);
        sInv[tid] = inv;
        sSh[tid]  = beta[o] - rmean[o] * inv + bias[o] * inv;
    }

    const int px_t = tid & 63;
    const int cl0  = tid >> 6;            // k-group this thread fills
    const float* xb = x + ((size_t)b << 20);

    float g0[8], g1[8], g2[8], g3[8];     // pending gather results
    int4 idP; float4 wgP;

    auto ISSUE = [&](int s2) {
        const int chunk = div9(s2), tap = s2 - 9 * chunk;
        idP = sidx[tap * 64 + px_t];
        wgP = swgt[tap * 64 + px_t];
        const float* xc = xb + (((chunk << 5) + cl0 * 8) << 12);
#pragma unroll
        for (int j2 = 0; j2 < 8; ++j2) {
            g0[j2] = xc[idP.x];
            g1[j2] = xc[idP.y];
            g2[j2] = xc[idP.z];
            g3[j2] = xc[idP.w];
            xc += 4096;
        }
    };
    auto CONSUME = [&](int buf) {
        short8 p;
#pragma unroll
        for (int j2 = 0; j2 < 8; ++j2) {
            float v = g0[j2] * wgP.x + g1[j2] * wgP.y +
                      g2[j2] * wgP.z + g3[j2] * wgP.w;
            p[j2] = f2bf(v);
        }
        *(short8*)(&S[buf][cl0][px_t][0]) = p;
    };

    // A-frag base: lane holds row o = base+(lane&15), k = (lane>>4)*8+j
    const short* wbase = wt2 + ((mhalf * 128 + wid * 32 + (lane & 15)) << 5)
                             + ((lane >> 4) << 3);
    const int bpx = lane & 15;
    const int bg  = lane >> 4;

    float4v acc[2][4];
#pragma unroll
    for (int mt = 0; mt < 2; ++mt)
#pragma unroll
        for (int nt = 0; nt < 4; ++nt) acc[mt][nt] = (float4v){0.f, 0.f, 0.f, 0.f};

    __syncthreads();             // stage-0 LDS ready

    // ---- pipeline prologue -------------------------------------------------
    ISSUE(0);
    CONSUME(0);
    ISSUE(1);
    short8 aC0 = *(const short8*)(wbase);
    short8 aC1 = *(const short8*)(wbase + 512);
    __syncthreads();             // S[0] written

    // ---- K loop ------------------------------------------------------------
#pragma unroll 1
    for (int s = 0; s < NS; ++s) {
        const int sn = (s + 1 < NS) ? (s + 1) : s;
        short8 aN0 = *(const short8*)(wbase + (size_t)sn * 8192);
        short8 aN1 = *(const short8*)(wbase + (size_t)sn * 8192 + 512);

        const int buf = s & 1;
        short8 b0 = *(const short8*)(&S[buf][bg][ 0 + bpx][0]);
        short8 b1 = *(const short8*)(&S[buf][bg][16 + bpx][0]);
        short8 b2 = *(const short8*)(&S[buf][bg][32 + bpx][0]);
        short8 b3 = *(const short8*)(&S[buf][bg][48 + bpx][0]);

        acc[0][0] = __builtin_amdgcn_mfma_f32_16x16x32_bf16(aC0, b0, acc[0][0], 0, 0, 0);
        acc[0][1] = __builtin_amdgcn_mfma_f32_16x16x32_bf16(aC0, b1, acc[0][1], 0, 0, 0);
        acc[0][2] = __builtin_amdgcn_mfma_f32_16x16x32_bf16(aC0, b2, acc[0][2], 0, 0, 0);
        acc[0][3] = __builtin_amdgcn_mfma_f32_16x16x32_bf16(aC0, b3, acc[0][3], 0, 0, 0);
        acc[1][0] = __builtin_amdgcn_mfma_f32_16x16x32_bf16(aC1, b0, acc[1][0], 0, 0, 0);
        acc[1][1] = __builtin_amdgcn_mfma_f32_16x16x32_bf16(aC1, b1, acc[1][1], 0, 0, 0);
        acc[1][2] = __builtin_amdgcn_mfma_f32_16x16x32_bf16(aC1, b2, acc[1][2], 0, 0, 0);
        acc[1][3] = __builtin_amdgcn_mfma_f32_16x16x32_bf16(aC1, b3, acc[1][3], 0, 0, 0);

        if (s < NS - 1) {
            CONSUME((s + 1) & 1);          // waits on gathers issued last iter
            if (s + 2 < NS) ISSUE(s + 2);  // gathers in flight across barrier
        }
        aC0 = aN0; aC1 = aN1;
        __syncthreads();
    }

    // ---- epilogue: BN+ReLU, D layout col=lane&15, row=(lane>>4)*4+r --------
    const int r4 = lane >> 4;
    float* ob = out + (((size_t)b * 256 + mhalf * 128) << 12) + (h << 6);
#pragma unroll
    for (int mt = 0; mt < 2; ++mt)
#pragma unroll
        for (int nt = 0; nt < 4; ++nt) {
            const int px = nt * 16 + bpx;
#pragma unroll
            for (int r = 0; r < 4; ++r) {
                const int oloc = wid * 32 + mt * 16 + r4 * 4 + r;
                const float v = acc[mt][nt][r] * sInv[oloc] + sSh[oloc];
                ob[((size_t)oloc << 12) + px] = fmaxf(v, 0.f);
            }
        }
}

// ---------------------------------------------------------------------------
extern "C" void kernel_launch(void* const* d_in, const int* in_sizes, int n_in,
                              void* d_out, int out_size, void* d_ws, size_t ws_size,
                              hipStream_t stream) {
    const float* x     = (const float*)d_in[0];
    const float* w_off = (const float*)d_in[1];
    const float* b_off = (const float*)d_in[2];
    const float* w     = (const float*)d_in[3];
    const float* bias  = (const float*)d_in[4];
    const float* gamma = (const float*)d_in[5];
    const float* beta  = (const float*)d_in[6];
    const float* rmean = (const float*)d_in[7];
    const float* rvar  = (const float*)d_in[8];
    float* out = (float*)d_out;

    float* om_part = (float*)d_ws;                            // QQ*4*27*4096 f32
    short* wt2     = (short*)(om_part + QQ * BB * 27 * 4096); // 72*256*32 bf16
    short* wo2     = wt2 + 72 * 256 * 32;                     // 72*32*32 bf16

    k_pack<<<2304, 256, 0, stream>>>(w, wt2);
    k_pack_off<<<288, 256, 0, stream>>>(w_off, wo2);
    k_off_mfma<<<512, 256, 0, stream>>>(x, wo2, om_part);
    k_main<<<512, 256, 0, stream>>>(x, om_part, b_off, wt2, bias, gamma,
                                    beta, rmean, rvar, out);
}

// Round 10
// 102.518 us; speedup vs baseline: 7.6186x; 2.2878x over previous
//
#include <hip/hip_runtime.h>

#define HH 64
#define WWD 64
#define CIN 256
#define OUTC 256
#define BB 4
#define KK 9
#define NS 72    // main K-steps: 8 chunks * 9 taps (channel-major)
#define NSO 36   // offset-conv K-steps per q-half
#define QQ 2     // offset-conv K-split partials

typedef __attribute__((ext_vector_type(8))) short short8;
typedef __attribute__((ext_vector_type(4))) short short4v;
typedef __attribute__((ext_vector_type(4))) float float4v;

__device__ __forceinline__ short f2bf(float f) {
    unsigned u = __builtin_bit_cast(unsigned, f);
    u += 0x7fffu + ((u >> 16) & 1u);          // round-to-nearest-even
    return (short)(u >> 16);
}
__device__ __forceinline__ float bf2f(short s) {
    unsigned u = ((unsigned)(unsigned short)s) << 16;
    return __builtin_bit_cast(float, u);
}
// floor(s/9) for s in [0,72)
__device__ __forceinline__ int div9(int s) { return (s * 57) >> 9; }

// ---------------------------------------------------------------------------
// Kernel P1: pack main weights bf16, CHANNEL-major K: s=chunk*9+tap
// wt2[s][o 256][kk 32], c = chunk*32+kk
// ---------------------------------------------------------------------------
__global__ __launch_bounds__(256) void k_pack(const float* __restrict__ w,
                                              short* __restrict__ wt2) {
    int gid = blockIdx.x * 256 + threadIdx.x;   // < 72*256*32
    int kk = gid & 31;
    int o  = (gid >> 5) & 255;
    int s  = gid >> 13;
    int chunk = div9(s), tap = s - 9 * chunk;
    int c = (chunk << 5) + kk;
    wt2[gid] = f2bf(w[(o * CIN + c) * 9 + tap]);
}

// ---------------------------------------------------------------------------
// Kernel P2: pack offset weights bf16: wo2[s][m 32][kk 32], rows 27..31 = 0
// ---------------------------------------------------------------------------
__global__ __launch_bounds__(256) void k_pack_off(const float* __restrict__ w_off,
                                                  short* __restrict__ wo2) {
    int gid = blockIdx.x * 256 + threadIdx.x;   // < 72*32*32
    int kk = gid & 31;
    int m  = (gid >> 5) & 31;
    int s  = gid >> 10;
    int chunk = div9(s), tap = s - 9 * chunk;
    int c = (chunk << 5) + kk;
    wo2[gid] = (m < 27) ? f2bf(w_off[(m * CIN + c) * 9 + tap]) : (short)0;
}

// ---------------------------------------------------------------------------
// Kernel 1: offset conv via bf16 MFMA. flat grid 512, XCD-swizzled.
// ---------------------------------------------------------------------------
__global__ __launch_bounds__(256) void k_off_mfma(const float* __restrict__ x,
                                                  const short* __restrict__ wo2,
                                                  float* __restrict__ om_part) {
    const int wgid = blockIdx.x;                       // 0..511
    const int swz  = ((wgid & 7) << 6) + (wgid >> 3);
    const int q = swz & 1;
    const int h = (swz >> 1) & 63;
    const int b = swz >> 7;
    const int tid = threadIdx.x;
    const int lane = tid & 63;
    const int wid  = tid >> 6;

    __shared__ short S[2][4][64][8];

    const int px_t = tid & 63;
    const int g    = tid >> 6;
    const float* xb = x + ((size_t)b << 20);

    float gv[8];
    auto ISSUE = [&](int s2) {
        const int chunk = div9(s2), tap = s2 - 9 * chunk;
        const int gy = h + tap / 3 - 1;
        const int gx = px_t + tap % 3 - 1;
        const bool ok = ((unsigned)gy < 64u) && ((unsigned)gx < 64u);
        const float* xc = xb + (((chunk << 5) + (g << 3)) << 12) + (gy << 6) + gx;
#pragma unroll
        for (int j = 0; j < 8; ++j)
            gv[j] = ok ? xc[(size_t)j << 12] : 0.f;
    };
    auto CONSUME = [&](int buf) {
        short8 p;
#pragma unroll
        for (int j = 0; j < 8; ++j) p[j] = f2bf(gv[j]);
        *(short8*)(&S[buf][g][px_t][0]) = p;
    };

    const int arow = lane & 15;
    const int akk  = (lane >> 4) << 3;
    const int bpx  = lane & 15;
    const int bg   = lane >> 4;

    float4v acc0 = {0.f, 0.f, 0.f, 0.f};
    float4v acc1 = {0.f, 0.f, 0.f, 0.f};

    const int s0 = q * NSO;
    ISSUE(s0); CONSUME(0); ISSUE(s0 + 1);
    const short* abase = wo2 + (size_t)s0 * 1024 + arow * 32 + akk;
    short8 aC0 = *(const short8*)(abase);
    short8 aC1 = *(const short8*)(abase + 512);
    __syncthreads();

#pragma unroll 1
    for (int ls = 0; ls < NSO; ++ls) {
        const int lsn = (ls + 1 < NSO) ? ls + 1 : ls;
        const short* an = wo2 + (size_t)(s0 + lsn) * 1024 + arow * 32 + akk;
        short8 aN0 = *(const short8*)(an);
        short8 aN1 = *(const short8*)(an + 512);

        short8 bf = *(const short8*)(&S[ls & 1][bg][(wid << 4) + bpx][0]);
        acc0 = __builtin_amdgcn_mfma_f32_16x16x32_bf16(aC0, bf, acc0, 0, 0, 0);
        acc1 = __builtin_amdgcn_mfma_f32_16x16x32_bf16(aC1, bf, acc1, 0, 0, 0);

        if (ls < NSO - 1) {
            CONSUME((ls + 1) & 1);
            if (ls + 2 < NSO) ISSUE(s0 + ls + 2);
        }
        aC0 = aN0; aC1 = aN1;
        __syncthreads();
    }

    const int pxo = (wid << 4) + bpx;
    float* ob = om_part + (((size_t)(q * BB + b) * 27) << 12) + (h << 6) + pxo;
#pragma unroll
    for (int r = 0; r < 4; ++r) {
        const int m0 = ((lane >> 4) << 2) + r;
        ob[(size_t)m0 << 12] = acc0[r];
        const int m1 = 16 + m0;
        if (m1 < 27) ob[(size_t)m1 << 12] = acc1[r];
    }
}

// ---------------------------------------------------------------------------
// Kernel 2: deformable conv via bf16 MFMA + bias/BN/ReLU.
// flat grid 256 (XCD-swizzled), block 512 (8 waves), M=256 x N=64, K=2304.
// Gathers from a 12-row x 64-col x 32-ch bf16 LDS window (per chunk);
// global fallback for samples outside the window (essentially never).
// ---------------------------------------------------------------------------
__global__ __launch_bounds__(512) void k_main(
    const float* __restrict__ x, const float* __restrict__ om_part,
    const float* __restrict__ b_off, const short* __restrict__ wt2,
    const float* __restrict__ bias, const float* __restrict__ gamma,
    const float* __restrict__ beta, const float* __restrict__ rmean,
    const float* __restrict__ rvar, float* __restrict__ out) {

    const int wgid = blockIdx.x;                    // 0..255
    const int swz  = ((wgid & 7) << 5) + (wgid >> 3);  // XCD-contiguous
    const int h = swz & 63;
    const int b = swz >> 6;
    const int tid  = threadIdx.x;
    const int lane = tid & 63;
    const int wid  = tid >> 6;

    __shared__ int4   sidx[576];          // window pixel offsets / fallback
    __shared__ float4 swgt[576];          // corner weights (incl. mask)
    __shared__ short  S[2][4][64][8];     // B-tile double buffer
    __shared__ short  xw[8 * 768 * 4];    // x window: [q 8][pix 768][4 ch]
    __shared__ float  sInv[256], sSh[256];

    // ---- stage 0: bilinear params per (tap,px); BN consts ------------------
    for (int j = tid; j < 576; j += 512) {
        const int k  = j >> 6;
        const int px = j & 63;
        const int sp = (h << 6) + px;
        float oy = b_off[k], ox = b_off[k + KK], mz = b_off[k + 2 * KK];
#pragma unroll
        for (int q = 0; q < QQ; ++q) {
            const float* bp = om_part + (size_t)((q * BB + b) * 27) * 4096 + sp;
            oy += bp[k * 4096];
            ox += bp[(k + KK) * 4096];
            mz += bp[(k + 2 * KK) * 4096];
        }
        const float mask = 1.f / (1.f + expf(-mz));
        const float py  = (float)h  - 1.f + (float)(k / 3) + oy;
        const float pxc = (float)px - 1.f + (float)(k % 3) + ox;
        const float y0f = floorf(py), x0f = floorf(pxc);
        const float ly = py - y0f, lx = pxc - x0f;
        const int y0 = (int)y0f, x0 = (int)x0f;

        float4 wg;
        {
            bool v = (y0 >= 0) && (y0 < HH) && (x0 >= 0) && (x0 < WWD);
            wg.x = v ? (1.f - ly) * (1.f - lx) * mask : 0.f;
        }
        {
            bool v = (y0 >= 0) && (y0 < HH) && (x0 + 1 >= 0) && (x0 + 1 < WWD);
            wg.y = v ? (1.f - ly) * lx * mask : 0.f;
        }
        {
            bool v = (y0 + 1 >= 0) && (y0 + 1 < HH) && (x0 >= 0) && (x0 < WWD);
            wg.z = v ? ly * (1.f - lx) * mask : 0.f;
        }
        {
            bool v = (y0 + 1 >= 0) && (y0 + 1 < HH) && (x0 + 1 >= 0) && (x0 + 1 < WWD);
            wg.w = v ? ly * lx * mask : 0.f;
        }
        const int cy0 = min(max(y0, 0), 63),     cy1 = min(max(y0 + 1, 0), 63);
        const int cx0 = min(max(x0, 0), 63),     cx1 = min(max(x0 + 1, 0), 63);
        const int li0 = cy0 - (h - 4),           li1 = cy1 - (h - 4);
        int4 id;
        if ((unsigned)li0 < 12u && (unsigned)li1 < 12u) {
            id.x = (li0 << 6) + cx0;  id.y = (li0 << 6) + cx1;
            id.z = (li1 << 6) + cx0;  id.w = (li1 << 6) + cx1;
        } else {                       // window miss -> global fallback
            id.x = -1; id.y = y0; id.z = x0; id.w = 0;
        }
        sidx[j] = id;
        swgt[j] = wg;
    }
    if (tid < 256) {
        const float inv = gamma[tid] * rsqrtf(rvar[tid] + 1e-5f);
        sInv[tid] = inv;
        sSh[tid]  = beta[tid] - rmean[tid] * inv + bias[tid] * inv;
    }

    const float* xb = x + ((size_t)b << 20);

    // ---- window staging: 12 rows x 64 cols x 32 ch (chunk) -> xw -----------
    auto STAGE = [&](int chunk) {
        const int col = tid & 63;
        const int sub = tid >> 6;                  // q-plane 0..7 (4 ch each)
        const float* xc0 = xb + ((size_t)((chunk << 5) + (sub << 2)) << 12) + col;
#pragma unroll
        for (int r = 0; r < 12; ++r) {
            const int gro = min(max(h - 4 + r, 0), 63) << 6;
            float v0 = xc0[gro];
            float v1 = xc0[gro + 4096];
            float v2 = xc0[gro + 8192];
            float v3 = xc0[gro + 12288];
            short4v p; p.x = f2bf(v0); p.y = f2bf(v1); p.z = f2bf(v2); p.w = f2bf(v3);
            *(short4v*)&xw[((sub * 768 + (r << 6) + col) << 2)] = p;
        }
    };

    // ---- sampling: thread = (g,px,half); 4 channels via 4x ds_read_b64 -----
    auto SAMPLE = [&](int s2) {
        const int cks = div9(s2);
        const int tap = s2 - 9 * cks;
        const int slot = tid & 255;
        const int g    = slot >> 6;
        const int px   = slot & 63;
        const int half = tid >> 8;
        const int q    = (g << 1) + half;
        const int4   pp = sidx[(tap << 6) + px];
        const float4 ww = swgt[(tap << 6) + px];
        float a0, a1, a2, a3;
        if (pp.x >= 0) {
            short4v c00 = *(const short4v*)&xw[((q * 768 + pp.x) << 2)];
            short4v c01 = *(const short4v*)&xw[((q * 768 + pp.y) << 2)];
            short4v c10 = *(const short4v*)&xw[((q * 768 + pp.z) << 2)];
            short4v c11 = *(const short4v*)&xw[((q * 768 + pp.w) << 2)];
            a0 = ww.x*bf2f(c00.x) + ww.y*bf2f(c01.x) + ww.z*bf2f(c10.x) + ww.w*bf2f(c11.x);
            a1 = ww.x*bf2f(c00.y) + ww.y*bf2f(c01.y) + ww.z*bf2f(c10.y) + ww.w*bf2f(c11.y);
            a2 = ww.x*bf2f(c00.z) + ww.y*bf2f(c01.z) + ww.z*bf2f(c10.z) + ww.w*bf2f(c11.z);
            a3 = ww.x*bf2f(c00.w) + ww.y*bf2f(c01.w) + ww.z*bf2f(c10.w) + ww.w*bf2f(c11.w);
        } else {                                   // global fallback (rare)
            const int y0 = pp.y, x0 = pp.z;
            const int cy0 = min(max(y0, 0), 63),     cy1 = min(max(y0 + 1, 0), 63);
            const int cx0 = min(max(x0, 0), 63),     cx1 = min(max(x0 + 1, 0), 63);
            const int i00 = (cy0 << 6) + cx0, i01 = (cy0 << 6) + cx1;
            const int i10 = (cy1 << 6) + cx0, i11 = (cy1 << 6) + cx1;
            const float* xc = xb + ((size_t)((cks << 5) + (q << 2)) << 12);
            a0 = ww.x*xc[i00] + ww.y*xc[i01] + ww.z*xc[i10] + ww.w*xc[i11]; xc += 4096;
            a1 = ww.x*xc[i00] + ww.y*xc[i01] + ww.z*xc[i10] + ww.w*xc[i11]; xc += 4096;
            a2 = ww.x*xc[i00] + ww.y*xc[i01] + ww.z*xc[i10] + ww.w*xc[i11]; xc += 4096;
            a3 = ww.x*xc[i00] + ww.y*xc[i01] + ww.z*xc[i10] + ww.w*xc[i11];
        }
        short4v rr; rr.x = f2bf(a0); rr.y = f2bf(a1); rr.z = f2bf(a2); rr.w = f2bf(a3);
        *(short4v*)&S[s2 & 1][g][px][half << 2] = rr;
    };

    // A-frag: wave wid owns rows wid*32..+31; lane row=(lane&15), k=(lane>>4)*8+j
    const short* wbase = wt2 + ((wid * 32 + (lane & 15)) << 5) + ((lane >> 4) << 3);
    const int bpx = lane & 15;
    const int bg  = lane >> 4;

    float4v acc[2][4];
#pragma unroll
    for (int mt = 0; mt < 2; ++mt)
#pragma unroll
        for (int nt = 0; nt < 4; ++nt) acc[mt][nt] = (float4v){0.f, 0.f, 0.f, 0.f};

    __syncthreads();             // params ready
    STAGE(0);
    __syncthreads();             // window chunk0 ready
    SAMPLE(0);
    short8 aC0 = *(const short8*)(wbase);
    short8 aC1 = *(const short8*)(wbase + 512);
    __syncthreads();             // S[0] ready

    // ---- K loop ------------------------------------------------------------
#pragma unroll 1
    for (int s = 0; s < NS; ++s) {
        const int sn = (s + 1 < NS) ? s + 1 : s;
        if (s + 1 < NS && div9(s + 1) != div9(s)) {
            STAGE(div9(s + 1));
            __syncthreads();     // new window ready before sampling from it
        }
        short8 aN0 = *(const short8*)(wbase + (size_t)sn * 8192);
        short8 aN1 = *(const short8*)(wbase + (size_t)sn * 8192 + 512);

        const int buf = s & 1;
        short8 b0 = *(const short8*)(&S[buf][bg][ 0 + bpx][0]);
        short8 b1 = *(const short8*)(&S[buf][bg][16 + bpx][0]);
        short8 b2 = *(const short8*)(&S[buf][bg][32 + bpx][0]);
        short8 b3 = *(const short8*)(&S[buf][bg][48 + bpx][0]);

        acc[0][0] = __builtin_amdgcn_mfma_f32_16x16x32_bf16(aC0, b0, acc[0][0], 0, 0, 0);
        acc[0][1] = __builtin_amdgcn_mfma_f32_16x16x32_bf16(aC0, b1, acc[0][1], 0, 0, 0);
        acc[0][2] = __builtin_amdgcn_mfma_f32_16x16x32_bf16(aC0, b2, acc[0][2], 0, 0, 0);
        acc[0][3] = __builtin_amdgcn_mfma_f32_16x16x32_bf16(aC0, b3, acc[0][3], 0, 0, 0);
        acc[1][0] = __builtin_amdgcn_mfma_f32_16x16x32_bf16(aC1, b0, acc[1][0], 0, 0, 0);
        acc[1][1] = __builtin_amdgcn_mfma_f32_16x16x32_bf16(aC1, b1, acc[1][1], 0, 0, 0);
        acc[1][2] = __builtin_amdgcn_mfma_f32_16x16x32_bf16(aC1, b2, acc[1][2], 0, 0, 0);
        acc[1][3] = __builtin_amdgcn_mfma_f32_16x16x32_bf16(aC1, b3, acc[1][3], 0, 0, 0);

        if (s + 1 < NS) SAMPLE(s + 1);
        aC0 = aN0; aC1 = aN1;
        __syncthreads();
    }

    // ---- epilogue: BN+ReLU; D layout col=lane&15, row=(lane>>4)*4+r --------
    const int r4 = lane >> 4;
    float* ob = out + (((size_t)b * 256) << 12) + (h << 6);
#pragma unroll
    for (int mt = 0; mt < 2; ++mt)
#pragma unroll
        for (int nt = 0; nt < 4; ++nt) {
            const int px = nt * 16 + bpx;
#pragma unroll
            for (int r = 0; r < 4; ++r) {
                const int o = wid * 32 + mt * 16 + r4 * 4 + r;
                const float v = acc[mt][nt][r] * sInv[o] + sSh[o];
                ob[((size_t)o << 12) + px] = fmaxf(v, 0.f);
            }
        }
}

// ---------------------------------------------------------------------------
extern "C" void kernel_launch(void* const* d_in, const int* in_sizes, int n_in,
                              void* d_out, int out_size, void* d_ws, size_t ws_size,
                              hipStream_t stream) {
    const float* x     = (const float*)d_in[0];
    const float* w_off = (const float*)d_in[1];
    const float* b_off = (const float*)d_in[2];
    const float* w     = (const float*)d_in[3];
    const float* bias  = (const float*)d_in[4];
    const float* gamma = (const float*)d_in[5];
    const float* beta  = (const float*)d_in[6];
    const float* rmean = (const float*)d_in[7];
    const float* rvar  = (const float*)d_in[8];
    float* out = (float*)d_out;

    float* om_part = (float*)d_ws;                            // QQ*4*27*4096 f32
    short* wt2     = (short*)(om_part + QQ * BB * 27 * 4096); // 72*256*32 bf16
    short* wo2     = wt2 + 72 * 256 * 32;                     // 72*32*32 bf16

    k_pack<<<2304, 256, 0, stream>>>(w, wt2);
    k_pack_off<<<288, 256, 0, stream>>>(w_off, wo2);
    k_off_mfma<<<512, 256, 0, stream>>>(x, wo2, om_part);
    k_main<<<256, 512, 0, stream>>>(x, om_part, b_off, wt2, bias, gamma,
                                    beta, rmean, rvar, out);
}

// Round 11
// 99.423 us; speedup vs baseline: 7.8558x; 1.0311x over previous
//
#include <hip/hip_runtime.h>

#define HH 64
#define WWD 64
#define CIN 256
#define OUTC 256
#define BB 4
#define KK 9
#define NSO 36   // offset-conv K-steps per q-half
#define QQ 2     // offset-conv K-split partials
#define NIT 40   // main loop: 8 chunks * (4 pairs + 1 single)

typedef __attribute__((ext_vector_type(8))) short short8;
typedef __attribute__((ext_vector_type(4))) short short4v;
typedef __attribute__((ext_vector_type(4))) unsigned short ushort4v;
typedef __attribute__((ext_vector_type(4))) float float4v;

__device__ __forceinline__ short f2bf(float f) {
    unsigned u = __builtin_bit_cast(unsigned, f);
    u += 0x7fffu + ((u >> 16) & 1u);          // round-to-nearest-even
    return (short)(u >> 16);
}
__device__ __forceinline__ float bf2f(short s) {
    unsigned u = ((unsigned)(unsigned short)s) << 16;
    return __builtin_bit_cast(float, u);
}
// floor(s/9) for s in [0,72)
__device__ __forceinline__ int div9(int s) { return (s * 57) >> 9; }

// ---------------------------------------------------------------------------
// Kernel P1: pack main weights bf16, CHANNEL-major K: s=chunk*9+tap
// wt2[s][o 256][kk 32], c = chunk*32+kk
// ---------------------------------------------------------------------------
__global__ __launch_bounds__(256) void k_pack(const float* __restrict__ w,
                                              short* __restrict__ wt2) {
    int gid = blockIdx.x * 256 + threadIdx.x;   // < 72*256*32
    int kk = gid & 31;
    int o  = (gid >> 5) & 255;
    int s  = gid >> 13;
    int chunk = div9(s), tap = s - 9 * chunk;
    int c = (chunk << 5) + kk;
    wt2[gid] = f2bf(w[(o * CIN + c) * 9 + tap]);
}

// ---------------------------------------------------------------------------
// Kernel P2: pack offset weights bf16: wo2[s][m 32][kk 32], rows 27..31 = 0
// ---------------------------------------------------------------------------
__global__ __launch_bounds__(256) void k_pack_off(const float* __restrict__ w_off,
                                                  short* __restrict__ wo2) {
    int gid = blockIdx.x * 256 + threadIdx.x;   // < 72*32*32
    int kk = gid & 31;
    int m  = (gid >> 5) & 31;
    int s  = gid >> 10;
    int chunk = div9(s), tap = s - 9 * chunk;
    int c = (chunk << 5) + kk;
    wo2[gid] = (m < 27) ? f2bf(w_off[(m * CIN + c) * 9 + tap]) : (short)0;
}

// ---------------------------------------------------------------------------
// Kernel 1: offset conv via bf16 MFMA. flat grid 512, XCD-swizzled.
// ---------------------------------------------------------------------------
__global__ __launch_bounds__(256) void k_off_mfma(const float* __restrict__ x,
                                                  const short* __restrict__ wo2,
                                                  float* __restrict__ om_part) {
    const int wgid = blockIdx.x;                       // 0..511
    const int swz  = ((wgid & 7) << 6) + (wgid >> 3);
    const int q = swz & 1;
    const int h = (swz >> 1) & 63;
    const int b = swz >> 7;
    const int tid = threadIdx.x;
    const int lane = tid & 63;
    const int wid  = tid >> 6;

    __shared__ short S[2][4][64][8];

    const int px_t = tid & 63;
    const int g    = tid >> 6;
    const float* xb = x + ((size_t)b << 20);

    float gv[8];
    auto ISSUE = [&](int s2) {
        const int chunk = div9(s2), tap = s2 - 9 * chunk;
        const int gy = h + tap / 3 - 1;
        const int gx = px_t + tap % 3 - 1;
        const bool ok = ((unsigned)gy < 64u) && ((unsigned)gx < 64u);
        const float* xc = xb + (((chunk << 5) + (g << 3)) << 12) + (gy << 6) + gx;
#pragma unroll
        for (int j = 0; j < 8; ++j)
            gv[j] = ok ? xc[(size_t)j << 12] : 0.f;
    };
    auto CONSUME = [&](int buf) {
        short8 p;
#pragma unroll
        for (int j = 0; j < 8; ++j) p[j] = f2bf(gv[j]);
        *(short8*)(&S[buf][g][px_t][0]) = p;
    };

    const int arow = lane & 15;
    const int akk  = (lane >> 4) << 3;
    const int bpx  = lane & 15;
    const int bg   = lane >> 4;

    float4v acc0 = {0.f, 0.f, 0.f, 0.f};
    float4v acc1 = {0.f, 0.f, 0.f, 0.f};

    const int s0 = q * NSO;
    ISSUE(s0); CONSUME(0); ISSUE(s0 + 1);
    const short* abase = wo2 + (size_t)s0 * 1024 + arow * 32 + akk;
    short8 aC0 = *(const short8*)(abase);
    short8 aC1 = *(const short8*)(abase + 512);
    __syncthreads();

#pragma unroll 1
    for (int ls = 0; ls < NSO; ++ls) {
        const int lsn = (ls + 1 < NSO) ? ls + 1 : ls;
        const short* an = wo2 + (size_t)(s0 + lsn) * 1024 + arow * 32 + akk;
        short8 aN0 = *(const short8*)(an);
        short8 aN1 = *(const short8*)(an + 512);

        short8 bf = *(const short8*)(&S[ls & 1][bg][(wid << 4) + bpx][0]);
        acc0 = __builtin_amdgcn_mfma_f32_16x16x32_bf16(aC0, bf, acc0, 0, 0, 0);
        acc1 = __builtin_amdgcn_mfma_f32_16x16x32_bf16(aC1, bf, acc1, 0, 0, 0);

        if (ls < NSO - 1) {
            CONSUME((ls + 1) & 1);
            if (ls + 2 < NSO) ISSUE(s0 + ls + 2);
        }
        aC0 = aN0; aC1 = aN1;
        __syncthreads();
    }

    const int pxo = (wid << 4) + bpx;
    float* ob = om_part + (((size_t)(q * BB + b) * 27) << 12) + (h << 6) + pxo;
#pragma unroll
    for (int r = 0; r < 4; ++r) {
        const int m0 = ((lane >> 4) << 2) + r;
        ob[(size_t)m0 << 12] = acc0[r];
        const int m1 = 16 + m0;
        if (m1 < 27) ob[(size_t)m1 << 12] = acc1[r];
    }
}

// ---------------------------------------------------------------------------
// Kernel 2: deformable conv via bf16 MFMA + bias/BN/ReLU.
// flat grid 256 (XCD-swizzled), block 512 (8 waves), M=256 x N=64, K=2304.
// xw: [pix 768][32ch] bf16 window with bank-swizzle pos=(g+p+(p>>2))&3.
// Two taps per iteration (4 pairs + 1 single per chunk) -> 40 iterations.
// ---------------------------------------------------------------------------
__global__ __launch_bounds__(512) void k_main(
    const float* __restrict__ x, const float* __restrict__ om_part,
    const float* __restrict__ b_off, const short* __restrict__ wt2,
    const float* __restrict__ bias, const float* __restrict__ gamma,
    const float* __restrict__ beta, const float* __restrict__ rmean,
    const float* __restrict__ rvar, float* __restrict__ out) {

    const int wgid = blockIdx.x;                    // 0..255
    const int swz  = ((wgid & 7) << 5) + (wgid >> 3);  // XCD-contiguous
    const int h = swz & 63;
    const int b = swz >> 6;
    const int tid  = threadIdx.x;
    const int lane = tid & 63;
    const int wid  = tid >> 6;

    __shared__ ushort4v sidx2[576];       // packed corners: (p<<6)|swz-base, or sentinel
    __shared__ ushort4v sw4[576];         // bf16 corner weights (mask folded)
    __shared__ short    S[2][2][4][64][8];// [buf][tap-in-pair][g][px][8k]
    __shared__ short    xw[768 * 32];     // [pix][32ch] bf16, swizzled 8ch-groups
    __shared__ float    sInv[256], sSh[256];

    // ---- stage 0: bilinear params per (tap,px); BN consts ------------------
    for (int j = tid; j < 576; j += 512) {
        const int k  = j >> 6;
        const int px = j & 63;
        const int sp = (h << 6) + px;
        float oy = b_off[k], ox = b_off[k + KK], mz = b_off[k + 2 * KK];
#pragma unroll
        for (int q = 0; q < QQ; ++q) {
            const float* bp = om_part + (size_t)((q * BB + b) * 27) * 4096 + sp;
            oy += bp[k * 4096];
            ox += bp[(k + KK) * 4096];
            mz += bp[(k + 2 * KK) * 4096];
        }
        const float mask = 1.f / (1.f + expf(-mz));
        const float py  = (float)h  - 1.f + (float)(k / 3) + oy;
        const float pxc = (float)px - 1.f + (float)(k % 3) + ox;
        const float y0f = floorf(py), x0f = floorf(pxc);
        const float ly = py - y0f, lx = pxc - x0f;
        const int y0 = (int)y0f, x0 = (int)x0f;

        float w00, w01, w10, w11;
        {
            bool v = (y0 >= 0) && (y0 < HH) && (x0 >= 0) && (x0 < WWD);
            w00 = v ? (1.f - ly) * (1.f - lx) * mask : 0.f;
        }
        {
            bool v = (y0 >= 0) && (y0 < HH) && (x0 + 1 < WWD) && (x0 + 1 >= 0);
            w01 = v ? (1.f - ly) * lx * mask : 0.f;
        }
        {
            bool v = (y0 + 1 >= 0) && (y0 + 1 < HH) && (x0 >= 0) && (x0 < WWD);
            w10 = v ? ly * (1.f - lx) * mask : 0.f;
        }
        {
            bool v = (y0 + 1 >= 0) && (y0 + 1 < HH) && (x0 + 1 >= 0) && (x0 + 1 < WWD);
            w11 = v ? ly * lx * mask : 0.f;
        }
        const int cy0 = min(max(y0, 0), 63),     cy1 = min(max(y0 + 1, 0), 63);
        const int cx0 = min(max(x0, 0), 63),     cx1 = min(max(x0 + 1, 0), 63);
        const int li0 = cy0 - (h - 4),           li1 = cy1 - (h - 4);
        ushort4v pv;
        if ((unsigned)li0 < 12u && (unsigned)li1 < 12u) {
            const int p00 = (li0 << 6) + cx0, p01 = (li0 << 6) + cx1;
            const int p10 = (li1 << 6) + cx0, p11 = (li1 << 6) + cx1;
            pv.x = (unsigned short)((p00 << 6) | ((p00 + (p00 >> 2)) & 3));
            pv.y = (unsigned short)((p01 << 6) | ((p01 + (p01 >> 2)) & 3));
            pv.z = (unsigned short)((p10 << 6) | ((p10 + (p10 >> 2)) & 3));
            pv.w = (unsigned short)((p11 << 6) | ((p11 + (p11 >> 2)) & 3));
        } else {                       // window miss -> global fallback
            pv.x = 0xFFFFu;
            pv.y = (unsigned short)(y0 + 32);
            pv.z = (unsigned short)(x0 + 32);
            pv.w = 0;
        }
        ushort4v wv;
        wv.x = (unsigned short)f2bf(w00);
        wv.y = (unsigned short)f2bf(w01);
        wv.z = (unsigned short)f2bf(w10);
        wv.w = (unsigned short)f2bf(w11);
        sidx2[j] = pv;
        sw4[j]   = wv;
    }
    if (tid < 256) {
        const float inv = gamma[tid] * rsqrtf(rvar[tid] + 1e-5f);
        sInv[tid] = inv;
        sSh[tid]  = beta[tid] - rmean[tid] * inv + bias[tid] * inv;
    }

    const float* xb = x + ((size_t)b << 20);

    // ---- window staging: [pix 768][32ch] bf16, swizzled --------------------
    auto STAGE = [&](int chunk) {
#pragma unroll
        for (int r6 = 0; r6 < 6; ++r6) {
            const int t   = r6 * 512 + tid;          // 0..3071
            const int g   = (t >> 8) / 3;            // 0..3 (768 = 3*256)
            const int pix = t - g * 768;
            const int wr  = pix >> 6, col = pix & 63;
            const int gro = (min(max(h - 4 + wr, 0), 63) << 6) + col;
            const float* xc = xb + ((size_t)((chunk << 5) + (g << 3)) << 12) + gro;
            short8 p;
#pragma unroll
            for (int j = 0; j < 8; ++j) p[j] = f2bf(xc[(size_t)j << 12]);
            const int pos = (g + pix + (pix >> 2)) & 3;
            *(short8*)&xw[pix * 32 + pos * 8] = p;
        }
    };

    // ---- sampling: thread=(tp,g,px): 8 channels via 4x ds_read_b128 --------
    auto SAMPLE = [&](int c2, int sub2, int ntaps2, int buf2) {
        const int tp = tid >> 8;                 // tap within pair
        if (tp < ntaps2) {
            const int slot = tid & 255;
            const int g  = slot >> 6;
            const int px = slot & 63;
            const int tap = sub2 * 2 + tp;       // local tap 0..8
            const int j = (tap << 6) + px;
            const ushort4v sv = sidx2[j];
            const ushort4v wv = sw4[j];
            const float w00 = bf2f((short)wv.x), w01 = bf2f((short)wv.y);
            const float w10 = bf2f((short)wv.z), w11 = bf2f((short)wv.w);
            float a[8];
            if (sv.x != 0xFFFFu) {
                const int o0 = ((sv.x & 0xFFC0u) >> 1) + (((sv.x + g) & 3u) << 3);
                const int o1 = ((sv.y & 0xFFC0u) >> 1) + (((sv.y + g) & 3u) << 3);
                const int o2 = ((sv.z & 0xFFC0u) >> 1) + (((sv.z + g) & 3u) << 3);
                const int o3 = ((sv.w & 0xFFC0u) >> 1) + (((sv.w + g) & 3u) << 3);
                const short8 c00 = *(const short8*)&xw[o0];
                const short8 c01 = *(const short8*)&xw[o1];
                const short8 c10 = *(const short8*)&xw[o2];
                const short8 c11 = *(const short8*)&xw[o3];
#pragma unroll
                for (int j2 = 0; j2 < 8; ++j2)
                    a[j2] = w00 * bf2f(c00[j2]) + w01 * bf2f(c01[j2])
                          + w10 * bf2f(c10[j2]) + w11 * bf2f(c11[j2]);
            } else {                             // global fallback (rare)
                const int y0 = (int)sv.y - 32, x0 = (int)sv.z - 32;
                const int cy0 = min(max(y0, 0), 63), cy1 = min(max(y0 + 1, 0), 63);
                const int cx0 = min(max(x0, 0), 63), cx1 = min(max(x0 + 1, 0), 63);
                const int i00 = (cy0 << 6) + cx0, i01 = (cy0 << 6) + cx1;
                const int i10 = (cy1 << 6) + cx0, i11 = (cy1 << 6) + cx1;
                const float* xc = xb + ((size_t)((c2 << 5) + (g << 3)) << 12);
#pragma unroll
                for (int j2 = 0; j2 < 8; ++j2) {
                    a[j2] = w00 * xc[i00] + w01 * xc[i01]
                          + w10 * xc[i10] + w11 * xc[i11];
                    xc += 4096;
                }
            }
            short8 rr;
#pragma unroll
            for (int j2 = 0; j2 < 8; ++j2) rr[j2] = f2bf(a[j2]);
            *(short8*)&S[buf2][tp][g][px][0] = rr;
        }
    };

    // A-frag: wave wid owns rows wid*32..+31; lane row=(lane&15), k=(lane>>4)*8+j
    const short* wbase = wt2 + ((wid * 32 + (lane & 15)) << 5) + ((lane >> 4) << 3);
    const int bpx = lane & 15;
    const int bg  = lane >> 4;

    float4v acc[2][4];
#pragma unroll
    for (int mt = 0; mt < 2; ++mt)
#pragma unroll
        for (int nt = 0; nt < 4; ++nt) acc[mt][nt] = (float4v){0.f, 0.f, 0.f, 0.f};

    __syncthreads();             // params ready
    STAGE(0);
    __syncthreads();             // window chunk0 ready
    SAMPLE(0, 0, 2, 0);          // taps 0,1 -> S[0]
    short8 aC00 = *(const short8*)(wbase);                 // s=0
    short8 aC01 = *(const short8*)(wbase + 512);
    short8 aC10 = *(const short8*)(wbase + 8192);          // s=1
    short8 aC11 = *(const short8*)(wbase + 8192 + 512);
    __syncthreads();             // S[0] ready

    // ---- main loop: 40 iterations ------------------------------------------
    int c = 0, sub = 0;
#pragma unroll 1
    for (int it = 0; it < NIT; ++it) {
        const int ntaps = (sub < 4) ? 2 : 1;
        int subn = sub + 1, cn = c;
        if (subn == 5) { subn = 0; cn = c + 1; }
        const int ntapsN = (subn < 4) ? 2 : 1;
        const int sN = cn * 9 + subn * 2;        // next iter's first k-step

        short8 aN00 = aC00, aN01 = aC01, aN10 = aC10, aN11 = aC11;
        if (it + 1 < NIT) {
            aN00 = *(const short8*)(wbase + (size_t)sN * 8192);
            aN01 = *(const short8*)(wbase + (size_t)sN * 8192 + 512);
            if (ntapsN == 2) {
                aN10 = *(const short8*)(wbase + (size_t)(sN + 1) * 8192);
                aN11 = *(const short8*)(wbase + (size_t)(sN + 1) * 8192 + 512);
            }
        }

        const int buf = it & 1;
        {
            const short* Sb = &S[buf][0][bg][bpx][0];
            short8 b0 = *(const short8*)(Sb);
            short8 b1 = *(const short8*)(Sb + 128);
            short8 b2 = *(const short8*)(Sb + 256);
            short8 b3 = *(const short8*)(Sb + 384);
            acc[0][0] = __builtin_amdgcn_mfma_f32_16x16x32_bf16(aC00, b0, acc[0][0], 0, 0, 0);
            acc[0][1] = __builtin_amdgcn_mfma_f32_16x16x32_bf16(aC00, b1, acc[0][1], 0, 0, 0);
            acc[0][2] = __builtin_amdgcn_mfma_f32_16x16x32_bf16(aC00, b2, acc[0][2], 0, 0, 0);
            acc[0][3] = __builtin_amdgcn_mfma_f32_16x16x32_bf16(aC00, b3, acc[0][3], 0, 0, 0);
            acc[1][0] = __builtin_amdgcn_mfma_f32_16x16x32_bf16(aC01, b0, acc[1][0], 0, 0, 0);
            acc[1][1] = __builtin_amdgcn_mfma_f32_16x16x32_bf16(aC01, b1, acc[1][1], 0, 0, 0);
            acc[1][2] = __builtin_amdgcn_mfma_f32_16x16x32_bf16(aC01, b2, acc[1][2], 0, 0, 0);
            acc[1][3] = __builtin_amdgcn_mfma_f32_16x16x32_bf16(aC01, b3, acc[1][3], 0, 0, 0);
        }
        if (ntaps == 2) {
            const short* Sb = &S[buf][1][bg][bpx][0];
            short8 b0 = *(const short8*)(Sb);
            short8 b1 = *(const short8*)(Sb + 128);
            short8 b2 = *(const short8*)(Sb + 256);
            short8 b3 = *(const short8*)(Sb + 384);
            acc[0][0] = __builtin_amdgcn_mfma_f32_16x16x32_bf16(aC10, b0, acc[0][0], 0, 0, 0);
            acc[0][1] = __builtin_amdgcn_mfma_f32_16x16x32_bf16(aC10, b1, acc[0][1], 0, 0, 0);
            acc[0][2] = __builtin_amdgcn_mfma_f32_16x16x32_bf16(aC10, b2, acc[0][2], 0, 0, 0);
            acc[0][3] = __builtin_amdgcn_mfma_f32_16x16x32_bf16(aC10, b3, acc[0][3], 0, 0, 0);
            acc[1][0] = __builtin_amdgcn_mfma_f32_16x16x32_bf16(aC11, b0, acc[1][0], 0, 0, 0);
            acc[1][1] = __builtin_amdgcn_mfma_f32_16x16x32_bf16(aC11, b1, acc[1][1], 0, 0, 0);
            acc[1][2] = __builtin_amdgcn_mfma_f32_16x16x32_bf16(aC11, b2, acc[1][2], 0, 0, 0);
            acc[1][3] = __builtin_amdgcn_mfma_f32_16x16x32_bf16(aC11, b3, acc[1][3], 0, 0, 0);
        }

        if (it + 1 < NIT) {
            if (sub == 4) {                      // next iter samples new chunk
                STAGE(cn);
                __syncthreads();                 // window cn ready
            }
            SAMPLE(cn, subn, ntapsN, (it + 1) & 1);
        }
        aC00 = aN00; aC01 = aN01; aC10 = aN10; aC11 = aN11;
        __syncthreads();
        c = cn; sub = subn;
    }

    // ---- epilogue: BN+ReLU; D layout col=lane&15, row=(lane>>4)*4+r --------
    const int r4 = lane >> 4;
    float* ob = out + (((size_t)b * 256) << 12) + (h << 6);
#pragma unroll
    for (int mt = 0; mt < 2; ++mt)
#pragma unroll
        for (int nt = 0; nt < 4; ++nt) {
            const int px = nt * 16 + bpx;
#pragma unroll
            for (int r = 0; r < 4; ++r) {
                const int o = wid * 32 + mt * 16 + r4 * 4 + r;
                const float v = acc[mt][nt][r] * sInv[o] + sSh[o];
                ob[((size_t)o << 12) + px] = fmaxf(v, 0.f);
            }
        }
}

// ---------------------------------------------------------------------------
extern "C" void kernel_launch(void* const* d_in, const int* in_sizes, int n_in,
                              void* d_out, int out_size, void* d_ws, size_t ws_size,
                              hipStream_t stream) {
    const float* x     = (const float*)d_in[0];
    const float* w_off = (const float*)d_in[1];
    const float* b_off = (const float*)d_in[2];
    const float* w     = (const float*)d_in[3];
    const float* bias  = (const float*)d_in[4];
    const float* gamma = (const float*)d_in[5];
    const float* beta  = (const float*)d_in[6];
    const float* rmean = (const float*)d_in[7];
    const float* rvar  = (const float*)d_in[8];
    float* out = (float*)d_out;

    float* om_part = (float*)d_ws;                            // QQ*4*27*4096 f32
    short* wt2     = (short*)(om_part + QQ * BB * 27 * 4096); // 72*256*32 bf16
    short* wo2     = wt2 + 72 * 256 * 32;                     // 72*32*32 bf16

    k_pack<<<2304, 256, 0, stream>>>(w, wt2);
    k_pack_off<<<288, 256, 0, stream>>>(w_off, wo2);
    k_off_mfma<<<512, 256, 0, stream>>>(x, wo2, om_part);
    k_main<<<256, 512, 0, stream>>>(x, om_part, b_off, wt2, bias, gamma,
                                    beta, rmean, rvar, out);
}

// Round 12
// 89.245 us; speedup vs baseline: 8.7518x; 1.1140x over previous
//
#include <hip/hip_runtime.h>

#define HH 64
#define WWD 64
#define CIN 256
#define OUTC 256
#define BB 4
#define KK 9
#define NSO 36   // offset-conv K-steps per q-half
#define QQ 2     // offset-conv K-split partials
#define NITH 20  // main loop per q-half: 4 chunks * (4 pairs + 1 single)

typedef __attribute__((ext_vector_type(8))) short short8;
typedef __attribute__((ext_vector_type(4))) short short4v;
typedef __attribute__((ext_vector_type(4))) unsigned short ushort4v;
typedef __attribute__((ext_vector_type(4))) float float4v;

__device__ __forceinline__ short f2bf(float f) {
    unsigned u = __builtin_bit_cast(unsigned, f);
    u += 0x7fffu + ((u >> 16) & 1u);          // round-to-nearest-even
    return (short)(u >> 16);
}
__device__ __forceinline__ float bf2f(short s) {
    unsigned u = ((unsigned)(unsigned short)s) << 16;
    return __builtin_bit_cast(float, u);
}
// floor(s/9) for s in [0,72)
__device__ __forceinline__ int div9(int s) { return (s * 57) >> 9; }

// ---------------------------------------------------------------------------
// Kernel P1: pack main weights bf16, CHANNEL-major K: s=chunk*9+tap
// wt2[s][o 256][kk 32], c = chunk*32+kk
// ---------------------------------------------------------------------------
__global__ __launch_bounds__(256) void k_pack(const float* __restrict__ w,
                                              short* __restrict__ wt2) {
    int gid = blockIdx.x * 256 + threadIdx.x;   // < 72*256*32
    int kk = gid & 31;
    int o  = (gid >> 5) & 255;
    int s  = gid >> 13;
    int chunk = div9(s), tap = s - 9 * chunk;
    int c = (chunk << 5) + kk;
    wt2[gid] = f2bf(w[(o * CIN + c) * 9 + tap]);
}

// ---------------------------------------------------------------------------
// Kernel P2: pack offset weights bf16: wo2[s][m 32][kk 32], rows 27..31 = 0
// ---------------------------------------------------------------------------
__global__ __launch_bounds__(256) void k_pack_off(const float* __restrict__ w_off,
                                                  short* __restrict__ wo2) {
    int gid = blockIdx.x * 256 + threadIdx.x;   // < 72*32*32
    int kk = gid & 31;
    int m  = (gid >> 5) & 31;
    int s  = gid >> 10;
    int chunk = div9(s), tap = s - 9 * chunk;
    int c = (chunk << 5) + kk;
    wo2[gid] = (m < 27) ? f2bf(w_off[(m * CIN + c) * 9 + tap]) : (short)0;
}

// ---------------------------------------------------------------------------
// Kernel 1: offset conv via bf16 MFMA. flat grid 512, XCD-swizzled.
// ---------------------------------------------------------------------------
__global__ __launch_bounds__(256) void k_off_mfma(const float* __restrict__ x,
                                                  const short* __restrict__ wo2,
                                                  float* __restrict__ om_part) {
    const int wgid = blockIdx.x;                       // 0..511
    const int swz  = ((wgid & 7) << 6) + (wgid >> 3);
    const int q = swz & 1;
    const int h = (swz >> 1) & 63;
    const int b = swz >> 7;
    const int tid = threadIdx.x;
    const int lane = tid & 63;
    const int wid  = tid >> 6;

    __shared__ short S[2][4][64][8];

    const int px_t = tid & 63;
    const int g    = tid >> 6;
    const float* xb = x + ((size_t)b << 20);

    float gv[8];
    auto ISSUE = [&](int s2) {
        const int chunk = div9(s2), tap = s2 - 9 * chunk;
        const int gy = h + tap / 3 - 1;
        const int gx = px_t + tap % 3 - 1;
        const bool ok = ((unsigned)gy < 64u) && ((unsigned)gx < 64u);
        const float* xc = xb + (((chunk << 5) + (g << 3)) << 12) + (gy << 6) + gx;
#pragma unroll
        for (int j = 0; j < 8; ++j)
            gv[j] = ok ? xc[(size_t)j << 12] : 0.f;
    };
    auto CONSUME = [&](int buf) {
        short8 p;
#pragma unroll
        for (int j = 0; j < 8; ++j) p[j] = f2bf(gv[j]);
        *(short8*)(&S[buf][g][px_t][0]) = p;
    };

    const int arow = lane & 15;
    const int akk  = (lane >> 4) << 3;
    const int bpx  = lane & 15;
    const int bg   = lane >> 4;

    float4v acc0 = {0.f, 0.f, 0.f, 0.f};
    float4v acc1 = {0.f, 0.f, 0.f, 0.f};

    const int s0 = q * NSO;
    ISSUE(s0); CONSUME(0); ISSUE(s0 + 1);
    const short* abase = wo2 + (size_t)s0 * 1024 + arow * 32 + akk;
    short8 aC0 = *(const short8*)(abase);
    short8 aC1 = *(const short8*)(abase + 512);
    __syncthreads();

#pragma unroll 1
    for (int ls = 0; ls < NSO; ++ls) {
        const int lsn = (ls + 1 < NSO) ? ls + 1 : ls;
        const short* an = wo2 + (size_t)(s0 + lsn) * 1024 + arow * 32 + akk;
        short8 aN0 = *(const short8*)(an);
        short8 aN1 = *(const short8*)(an + 512);

        short8 bf = *(const short8*)(&S[ls & 1][bg][(wid << 4) + bpx][0]);
        acc0 = __builtin_amdgcn_mfma_f32_16x16x32_bf16(aC0, bf, acc0, 0, 0, 0);
        acc1 = __builtin_amdgcn_mfma_f32_16x16x32_bf16(aC1, bf, acc1, 0, 0, 0);

        if (ls < NSO - 1) {
            CONSUME((ls + 1) & 1);
            if (ls + 2 < NSO) ISSUE(s0 + ls + 2);
        }
        aC0 = aN0; aC1 = aN1;
        __syncthreads();
    }

    const int pxo = (wid << 4) + bpx;
    float* ob = om_part + (((size_t)(q * BB + b) * 27) << 12) + (h << 6) + pxo;
#pragma unroll
    for (int r = 0; r < 4; ++r) {
        const int m0 = ((lane >> 4) << 2) + r;
        ob[(size_t)m0 << 12] = acc0[r];
        const int m1 = 16 + m0;
        if (m1 < 27) ob[(size_t)m1 << 12] = acc1[r];
    }
}

// ---------------------------------------------------------------------------
// Kernel 2: deformable conv partial (K-split in 2) via bf16 MFMA, raw sums.
// flat grid 512 (XCD-swizzled), block 512 (8 waves): q half-K per (h,b).
// q=0 -> raw sums into d_out; q=1 -> raw sums into part1 (ws).
// xw: [pix 768][32ch] bf16 window, bank-swizzle pos=(g+p+(p>>2))&3.
// ---------------------------------------------------------------------------
__global__ __launch_bounds__(512) void k_main(
    const float* __restrict__ x, const float* __restrict__ om_part,
    const float* __restrict__ b_off, const short* __restrict__ wt2,
    float* __restrict__ outr, float* __restrict__ part1) {

    const int wgid = blockIdx.x;                       // 0..511
    const int swz  = ((wgid & 7) << 6) + (wgid >> 3);  // XCD-contiguous
    const int q = swz & 1;                             // K half
    const int h = (swz >> 1) & 63;
    const int b = swz >> 7;
    const int tid  = threadIdx.x;
    const int lane = tid & 63;
    const int wid  = tid >> 6;

    __shared__ ushort4v sidx2[576];       // packed corners or sentinel
    __shared__ ushort4v sw4[576];         // bf16 corner weights (mask folded)
    __shared__ short    S[2][2][4][64][8];// [buf][tap-in-pair][g][px][8k]
    __shared__ short    xw[768 * 32];     // [pix][32ch] bf16, swizzled

    // ---- stage 0: bilinear params per (tap,px) -----------------------------
    for (int j = tid; j < 576; j += 512) {
        const int k  = j >> 6;
        const int px = j & 63;
        const int sp = (h << 6) + px;
        float oy = b_off[k], ox = b_off[k + KK], mz = b_off[k + 2 * KK];
#pragma unroll
        for (int qq = 0; qq < QQ; ++qq) {
            const float* bp = om_part + (size_t)((qq * BB + b) * 27) * 4096 + sp;
            oy += bp[k * 4096];
            ox += bp[(k + KK) * 4096];
            mz += bp[(k + 2 * KK) * 4096];
        }
        const float mask = 1.f / (1.f + expf(-mz));
        const float py  = (float)h  - 1.f + (float)(k / 3) + oy;
        const float pxc = (float)px - 1.f + (float)(k % 3) + ox;
        const float y0f = floorf(py), x0f = floorf(pxc);
        const float ly = py - y0f, lx = pxc - x0f;
        const int y0 = (int)y0f, x0 = (int)x0f;

        float w00, w01, w10, w11;
        {
            bool v = (y0 >= 0) && (y0 < HH) && (x0 >= 0) && (x0 < WWD);
            w00 = v ? (1.f - ly) * (1.f - lx) * mask : 0.f;
        }
        {
            bool v = (y0 >= 0) && (y0 < HH) && (x0 + 1 < WWD) && (x0 + 1 >= 0);
            w01 = v ? (1.f - ly) * lx * mask : 0.f;
        }
        {
            bool v = (y0 + 1 >= 0) && (y0 + 1 < HH) && (x0 >= 0) && (x0 < WWD);
            w10 = v ? ly * (1.f - lx) * mask : 0.f;
        }
        {
            bool v = (y0 + 1 >= 0) && (y0 + 1 < HH) && (x0 + 1 >= 0) && (x0 + 1 < WWD);
            w11 = v ? ly * lx * mask : 0.f;
        }
        const int cy0 = min(max(y0, 0), 63),     cy1 = min(max(y0 + 1, 0), 63);
        const int cx0 = min(max(x0, 0), 63),     cx1 = min(max(x0 + 1, 0), 63);
        const int li0 = cy0 - (h - 4),           li1 = cy1 - (h - 4);
        ushort4v pv;
        if ((unsigned)li0 < 12u && (unsigned)li1 < 12u) {
            const int p00 = (li0 << 6) + cx0, p01 = (li0 << 6) + cx1;
            const int p10 = (li1 << 6) + cx0, p11 = (li1 << 6) + cx1;
            pv.x = (unsigned short)((p00 << 6) | ((p00 + (p00 >> 2)) & 3));
            pv.y = (unsigned short)((p01 << 6) | ((p01 + (p01 >> 2)) & 3));
            pv.z = (unsigned short)((p10 << 6) | ((p10 + (p10 >> 2)) & 3));
            pv.w = (unsigned short)((p11 << 6) | ((p11 + (p11 >> 2)) & 3));
        } else {                       // window miss -> global fallback
            pv.x = 0xFFFFu;
            pv.y = (unsigned short)(y0 + 32);
            pv.z = (unsigned short)(x0 + 32);
            pv.w = 0;
        }
        ushort4v wv;
        wv.x = (unsigned short)f2bf(w00);
        wv.y = (unsigned short)f2bf(w01);
        wv.z = (unsigned short)f2bf(w10);
        wv.w = (unsigned short)f2bf(w11);
        sidx2[j] = pv;
        sw4[j]   = wv;
    }

    const float* xb = x + ((size_t)b << 20);

    // ---- window staging: [pix 768][32ch] bf16, swizzled --------------------
    auto STAGE = [&](int chunk) {
#pragma unroll
        for (int r6 = 0; r6 < 6; ++r6) {
            const int t   = r6 * 512 + tid;          // 0..3071
            const int g   = (t >> 8) / 3;            // 0..3 (768 = 3*256)
            const int pix = t - g * 768;
            const int wr  = pix >> 6, col = pix & 63;
            const int gro = (min(max(h - 4 + wr, 0), 63) << 6) + col;
            const float* xc = xb + ((size_t)((chunk << 5) + (g << 3)) << 12) + gro;
            short8 p;
#pragma unroll
            for (int j = 0; j < 8; ++j) p[j] = f2bf(xc[(size_t)j << 12]);
            const int pos = (g + pix + (pix >> 2)) & 3;
            *(short8*)&xw[pix * 32 + pos * 8] = p;
        }
    };

    // ---- sampling: thread=(tp,g,px): 8 channels via 4x ds_read_b128 --------
    auto SAMPLE = [&](int c2, int sub2, int ntaps2, int buf2) {
        const int tp = tid >> 8;                 // tap within pair
        if (tp < ntaps2) {
            const int slot = tid & 255;
            const int g  = slot >> 6;
            const int px = slot & 63;
            const int tap = sub2 * 2 + tp;       // local tap 0..8
            const int j = (tap << 6) + px;
            const ushort4v sv = sidx2[j];
            const ushort4v wv = sw4[j];
            const float w00 = bf2f((short)wv.x), w01 = bf2f((short)wv.y);
            const float w10 = bf2f((short)wv.z), w11 = bf2f((short)wv.w);
            float a[8];
            if (sv.x != 0xFFFFu) {
                const int o0 = ((sv.x & 0xFFC0u) >> 1) + (((sv.x + g) & 3u) << 3);
                const int o1 = ((sv.y & 0xFFC0u) >> 1) + (((sv.y + g) & 3u) << 3);
                const int o2 = ((sv.z & 0xFFC0u) >> 1) + (((sv.z + g) & 3u) << 3);
                const int o3 = ((sv.w & 0xFFC0u) >> 1) + (((sv.w + g) & 3u) << 3);
                const short8 c00 = *(const short8*)&xw[o0];
                const short8 c01 = *(const short8*)&xw[o1];
                const short8 c10 = *(const short8*)&xw[o2];
                const short8 c11 = *(const short8*)&xw[o3];
#pragma unroll
                for (int j2 = 0; j2 < 8; ++j2)
                    a[j2] = w00 * bf2f(c00[j2]) + w01 * bf2f(c01[j2])
                          + w10 * bf2f(c10[j2]) + w11 * bf2f(c11[j2]);
            } else {                             // global fallback (rare)
                const int y0 = (int)sv.y - 32, x0 = (int)sv.z - 32;
                const int cy0 = min(max(y0, 0), 63), cy1 = min(max(y0 + 1, 0), 63);
                const int cx0 = min(max(x0, 0), 63), cx1 = min(max(x0 + 1, 0), 63);
                const int i00 = (cy0 << 6) + cx0, i01 = (cy0 << 6) + cx1;
                const int i10 = (cy1 << 6) + cx0, i11 = (cy1 << 6) + cx1;
                const float* xc = xb + ((size_t)((c2 << 5) + (g << 3)) << 12);
#pragma unroll
                for (int j2 = 0; j2 < 8; ++j2) {
                    a[j2] = w00 * xc[i00] + w01 * xc[i01]
                          + w10 * xc[i10] + w11 * xc[i11];
                    xc += 4096;
                }
            }
            short8 rr;
#pragma unroll
            for (int j2 = 0; j2 < 8; ++j2) rr[j2] = f2bf(a[j2]);
            *(short8*)&S[buf2][tp][g][px][0] = rr;
        }
    };

    // A-frag: wave wid owns rows wid*32..+31; lane row=(lane&15), k=(lane>>4)*8+j
    const short* wbase = wt2 + ((wid * 32 + (lane & 15)) << 5) + ((lane >> 4) << 3);
    const int bpx = lane & 15;
    const int bg  = lane >> 4;

    float4v acc[2][4];
#pragma unroll
    for (int mt = 0; mt < 2; ++mt)
#pragma unroll
        for (int nt = 0; nt < 4; ++nt) acc[mt][nt] = (float4v){0.f, 0.f, 0.f, 0.f};

    const int c0 = q * 4;                 // this block's chunk range [c0, c0+4)
    const int sA0 = c0 * 9;

    __syncthreads();             // params ready
    STAGE(c0);
    __syncthreads();             // window chunk c0 ready
    SAMPLE(c0, 0, 2, 0);         // taps 0,1 -> S[0]
    short8 aC00 = *(const short8*)(wbase + (size_t)sA0 * 8192);
    short8 aC01 = *(const short8*)(wbase + (size_t)sA0 * 8192 + 512);
    short8 aC10 = *(const short8*)(wbase + (size_t)(sA0 + 1) * 8192);
    short8 aC11 = *(const short8*)(wbase + (size_t)(sA0 + 1) * 8192 + 512);
    __syncthreads();             // S[0] ready

    // ---- main loop: 20 iterations ------------------------------------------
    int c = c0, sub = 0;
#pragma unroll 1
    for (int it = 0; it < NITH; ++it) {
        const int ntaps = (sub < 4) ? 2 : 1;
        int subn = sub + 1, cn = c;
        if (subn == 5) { subn = 0; cn = c + 1; }
        const int ntapsN = (subn < 4) ? 2 : 1;
        const int sN = cn * 9 + subn * 2;        // next iter's first k-step

        short8 aN00 = aC00, aN01 = aC01, aN10 = aC10, aN11 = aC11;
        if (it + 1 < NITH) {
            aN00 = *(const short8*)(wbase + (size_t)sN * 8192);
            aN01 = *(const short8*)(wbase + (size_t)sN * 8192 + 512);
            if (ntapsN == 2) {
                aN10 = *(const short8*)(wbase + (size_t)(sN + 1) * 8192);
                aN11 = *(const short8*)(wbase + (size_t)(sN + 1) * 8192 + 512);
            }
        }

        const int buf = it & 1;
        {
            const short* Sb = &S[buf][0][bg][bpx][0];
            short8 b0 = *(const short8*)(Sb);
            short8 b1 = *(const short8*)(Sb + 128);
            short8 b2 = *(const short8*)(Sb + 256);
            short8 b3 = *(const short8*)(Sb + 384);
            acc[0][0] = __builtin_amdgcn_mfma_f32_16x16x32_bf16(aC00, b0, acc[0][0], 0, 0, 0);
            acc[0][1] = __builtin_amdgcn_mfma_f32_16x16x32_bf16(aC00, b1, acc[0][1], 0, 0, 0);
            acc[0][2] = __builtin_amdgcn_mfma_f32_16x16x32_bf16(aC00, b2, acc[0][2], 0, 0, 0);
            acc[0][3] = __builtin_amdgcn_mfma_f32_16x16x32_bf16(aC00, b3, acc[0][3], 0, 0, 0);
            acc[1][0] = __builtin_amdgcn_mfma_f32_16x16x32_bf16(aC01, b0, acc[1][0], 0, 0, 0);
            acc[1][1] = __builtin_amdgcn_mfma_f32_16x16x32_bf16(aC01, b1, acc[1][1], 0, 0, 0);
            acc[1][2] = __builtin_amdgcn_mfma_f32_16x16x32_bf16(aC01, b2, acc[1][2], 0, 0, 0);
            acc[1][3] = __builtin_amdgcn_mfma_f32_16x16x32_bf16(aC01, b3, acc[1][3], 0, 0, 0);
        }
        if (ntaps == 2) {
            const short* Sb = &S[buf][1][bg][bpx][0];
            short8 b0 = *(const short8*)(Sb);
            short8 b1 = *(const short8*)(Sb + 128);
            short8 b2 = *(const short8*)(Sb + 256);
            short8 b3 = *(const short8*)(Sb + 384);
            acc[0][0] = __builtin_amdgcn_mfma_f32_16x16x32_bf16(aC10, b0, acc[0][0], 0, 0, 0);
            acc[0][1] = __builtin_amdgcn_mfma_f32_16x16x32_bf16(aC10, b1, acc[0][1], 0, 0, 0);
            acc[0][2] = __builtin_amdgcn_mfma_f32_16x16x32_bf16(aC10, b2, acc[0][2], 0, 0, 0);
            acc[0][3] = __builtin_amdgcn_mfma_f32_16x16x32_bf16(aC10, b3, acc[0][3], 0, 0, 0);
            acc[1][0] = __builtin_amdgcn_mfma_f32_16x16x32_bf16(aC11, b0, acc[1][0], 0, 0, 0);
            acc[1][1] = __builtin_amdgcn_mfma_f32_16x16x32_bf16(aC11, b1, acc[1][1], 0, 0, 0);
            acc[1][2] = __builtin_amdgcn_mfma_f32_16x16x32_bf16(aC11, b2, acc[1][2], 0, 0, 0);
            acc[1][3] = __builtin_amdgcn_mfma_f32_16x16x32_bf16(aC11, b3, acc[1][3], 0, 0, 0);
        }

        if (it + 1 < NITH) {
            if (sub == 4) {                      // next iter samples new chunk
                STAGE(cn);
                __syncthreads();                 // window cn ready
            }
            SAMPLE(cn, subn, ntapsN, (it + 1) & 1);
        }
        aC00 = aN00; aC01 = aN01; aC10 = aN10; aC11 = aN11;
        __syncthreads();
        c = cn; sub = subn;
    }

    // ---- epilogue: raw partial sums; D layout col=lane&15, row=(lane>>4)*4+r
    const int r4 = lane >> 4;
    float* ob = (q == 0 ? outr : part1) + (((size_t)b * 256) << 12) + (h << 6);
#pragma unroll
    for (int mt = 0; mt < 2; ++mt)
#pragma unroll
        for (int nt = 0; nt < 4; ++nt) {
            const int px = nt * 16 + bpx;
#pragma unroll
            for (int r = 0; r < 4; ++r) {
                const int o = wid * 32 + mt * 16 + r4 * 4 + r;
                ob[((size_t)o << 12) + px] = acc[mt][nt][r];
            }
        }
}

// ---------------------------------------------------------------------------
// Kernel 3: sum partials + bias + BN + ReLU, in-place on d_out. float4.
// ---------------------------------------------------------------------------
__global__ __launch_bounds__(256) void k_bn(const float* __restrict__ part1,
                                            const float* __restrict__ bias,
                                            const float* __restrict__ gamma,
                                            const float* __restrict__ beta,
                                            const float* __restrict__ rmean,
                                            const float* __restrict__ rvar,
                                            float* __restrict__ out) {
    const int NTOT4 = BB * OUTC * 4096 / 4;          // 1,048,576 float4
    int i = blockIdx.x * 256 + threadIdx.x;
    const int stride = gridDim.x * 256;
#pragma unroll 1
    for (; i < NTOT4; i += stride) {
        const int e0 = i << 2;
        const int o  = (e0 >> 12) & 255;             // channel (wave-uniform)
        const float inv = gamma[o] * rsqrtf(rvar[o] + 1e-5f);
        const float sh  = beta[o] - rmean[o] * inv + bias[o] * inv;
        float4 a = ((const float4*)out)[i];
        float4 p = ((const float4*)part1)[i];
        float4 v;
        v.x = fmaxf((a.x + p.x) * inv + sh, 0.f);
        v.y = fmaxf((a.y + p.y) * inv + sh, 0.f);
        v.z = fmaxf((a.z + p.z) * inv + sh, 0.f);
        v.w = fmaxf((a.w + p.w) * inv + sh, 0.f);
        ((float4*)out)[i] = v;
    }
}

// ---------------------------------------------------------------------------
extern "C" void kernel_launch(void* const* d_in, const int* in_sizes, int n_in,
                              void* d_out, int out_size, void* d_ws, size_t ws_size,
                              hipStream_t stream) {
    const float* x     = (const float*)d_in[0];
    const float* w_off = (const float*)d_in[1];
    const float* b_off = (const float*)d_in[2];
    const float* w     = (const float*)d_in[3];
    const float* bias  = (const float*)d_in[4];
    const float* gamma = (const float*)d_in[5];
    const float* beta  = (const float*)d_in[6];
    const float* rmean = (const float*)d_in[7];
    const float* rvar  = (const float*)d_in[8];
    float* out = (float*)d_out;

    float* om_part = (float*)d_ws;                            // QQ*4*27*4096 f32
    short* wt2     = (short*)(om_part + QQ * BB * 27 * 4096); // 72*256*32 bf16
    short* wo2     = wt2 + 72 * 256 * 32;                     // 72*32*32 bf16
    float* part1   = (float*)(wo2 + 72 * 32 * 32);            // 4*256*4096 f32

    k_pack<<<2304, 256, 0, stream>>>(w, wt2);
    k_pack_off<<<288, 256, 0, stream>>>(w_off, wo2);
    k_off_mfma<<<512, 256, 0, stream>>>(x, wo2, om_part);
    k_main<<<512, 512, 0, stream>>>(x, om_part, b_off, wt2, out, part1);
    k_bn<<<2048, 256, 0, stream>>>(part1, bias, gamma, beta, rmean, rvar, out);
}